// Round 15
// baseline (1310.604 us; speedup 1.0000x reference)
//
#include <hip/hip_runtime.h>
#include <math.h>

#define TLEN 1024
#define DM   768
#define NH   12
#define HSZ  64
#define DF_  3072
#define NL   12
#define VC   50257
#define VCP  50304          // VC padded to 64
#define NPAN (VCP/128)      // 393 LM N-panels

typedef __attribute__((ext_vector_type(8))) short bf16x8;
typedef __attribute__((ext_vector_type(4))) float f32x4;

__device__ __forceinline__ float gelu_exact(float x){
  return 0.5f * x * (1.0f + erff(x * 0.70710678118654752f));
}
__device__ __forceinline__ short f2bf(float f){
  union { float f; unsigned u; } x; x.f = f;
  unsigned r = x.u + 0x7fffu + ((x.u >> 16) & 1u);
  return (short)(r >> 16);
}
__device__ __forceinline__ void gl16(const void* g, void* l){
  __builtin_amdgcn_global_load_lds(
      (const __attribute__((address_space(1))) unsigned int*)g,
      (__attribute__((address_space(3))) unsigned int*)l, 16, 0, 0);
}

// ---------------- embedding fused with layer-0 ln1: wave per row ------------
__global__ __launch_bounds__(256) void embedln_k(const int* __restrict__ x,
    const float* __restrict__ wte, const float* __restrict__ wpe,
    const float* __restrict__ sc, const float* __restrict__ bi,
    float* __restrict__ h, short* __restrict__ out)
{
  int w = threadIdx.x >> 6, lane = threadIdx.x & 63;
  int t = blockIdx.x * 4 + w;
  int tok = x[t];
  size_t off = (size_t)t * DM;
  float v[12];
  float s = 0.f, s2 = 0.f;
  #pragma unroll
  for (int i = 0; i < 12; i++){
    int c = lane + i * 64;
    float xv = wte[(size_t)tok * DM + c] + wpe[off + c];
    h[off + c] = xv;
    v[i] = xv; s += xv; s2 += xv * xv;
  }
  #pragma unroll
  for (int o = 32; o; o >>= 1){ s += __shfl_xor(s, o); s2 += __shfl_xor(s2, o); }
  float mu = s * (1.0f / DM);
  float var = s2 * (1.0f / DM) - mu * mu;
  float rs = rsqrtf(var + 1e-5f);
  #pragma unroll
  for (int i = 0; i < 12; i++){
    int c = lane + i * 64;
    out[off + c] = f2bf((v[i] - mu) * rs * sc[c] + bi[c]);
  }
}

// ---------------- layernorm: fp32 in, bf16 out ------------------------------
__global__ __launch_bounds__(256) void ln_k(const float* __restrict__ in,
    const float* __restrict__ sc, const float* __restrict__ bi,
    short* __restrict__ out)
{
  int w = threadIdx.x >> 6, lane = threadIdx.x & 63;
  int row = blockIdx.x * 4 + w;
  const float* r = in + (size_t)row * DM;
  float v[12];
  float s = 0.f, s2 = 0.f;
  #pragma unroll
  for (int i = 0; i < 12; i++){
    float xv = r[lane + i * 64];
    v[i] = xv; s += xv; s2 += xv * xv;
  }
  #pragma unroll
  for (int o = 32; o; o >>= 1){ s += __shfl_xor(s, o); s2 += __shfl_xor(s2, o); }
  float mu  = s * (1.0f / DM);
  float var = s2 * (1.0f / DM) - mu * mu;
  float rs  = rsqrtf(var + 1e-5f);
  short* o = out + (size_t)row * DM;
  #pragma unroll
  for (int i = 0; i < 12; i++){
    int c = lane + i * 64;
    o[c] = f2bf((v[i] - mu) * rs * sc[c] + bi[c]);
  }
}

// ---------------- transpose-cast: W [K][N] f32 -> WT [Nt*64][K] bf16 --------
__global__ __launch_bounds__(256) void tc_k(const float* __restrict__ in,
    short* __restrict__ out, int K, int N, int ntiles, int per_mat,
    size_t in_stride, size_t out_stride)
{
  __shared__ short sh[64][65];
  int b = blockIdx.x;
  int l = b / per_mat, r = b - l * per_mat;
  int nt = r % ntiles, kt = r / ntiles;
  const float* ip = in + (size_t)l * in_stride;
  short* op = out + (size_t)l * out_stride;
  int n0 = nt * 64, k0 = kt * 64;
  int tid = threadIdx.x;
  if ((N & 3) == 0){
    #pragma unroll
    for (int it = 0; it < 4; it++){
      int idx = it * 256 + tid;
      int k = idx >> 4, n4 = (idx & 15) * 4;
      float4 v = *(const float4*)(ip + (size_t)(k0 + k) * N + n0 + n4);
      sh[k][n4+0] = f2bf(v.x); sh[k][n4+1] = f2bf(v.y);
      sh[k][n4+2] = f2bf(v.z); sh[k][n4+3] = f2bf(v.w);
    }
  } else {
    #pragma unroll
    for (int it = 0; it < 16; it++){
      int idx = it * 256 + tid;
      int k = idx >> 6, n = idx & 63;
      float v = (n0 + n < N) ? ip[(size_t)(k0 + k) * N + n0 + n] : 0.f;
      sh[k][n] = f2bf(v);
    }
  }
  __syncthreads();
  #pragma unroll
  for (int it = 0; it < 2; it++){
    int n = it * 32 + (tid >> 3);
    int kc = (tid & 7) * 8;
    bf16x8 v;
    #pragma unroll
    for (int u = 0; u < 8; u++) v[u] = sh[kc + u][n];
    *(bf16x8*)(op + (size_t)(n0 + n) * K + k0 + kc) = v;
  }
}

// ---------------- QKV transpose-cast: [L][H][768][64] x3 -> [L][2304][768] --
__global__ __launch_bounds__(256) void tcqkv_k(const float* __restrict__ Wq,
    const float* __restrict__ Wk, const float* __restrict__ Wv,
    short* __restrict__ out)
{
  __shared__ short sh[64][65];
  int b = blockIdx.x;            // L*H*12
  int l = b / 144; int r = b - l * 144;
  int h = r / 12, kt = r - h * 12;
  int tid = threadIdx.x;
  for (int p = 0; p < 3; p++){
    const float* ip = (p == 0 ? Wq : p == 1 ? Wk : Wv)
                      + ((size_t)(l * NH + h) * DM + kt * 64) * 64;
    if (p) __syncthreads();
    #pragma unroll
    for (int it = 0; it < 4; it++){
      int idx = it * 256 + tid;
      int k = idx >> 4, e4 = (idx & 15) * 4;
      float4 v = *(const float4*)(ip + (size_t)k * 64 + e4);
      sh[k][e4+0] = f2bf(v.x); sh[k][e4+1] = f2bf(v.y);
      sh[k][e4+2] = f2bf(v.z); sh[k][e4+3] = f2bf(v.w);
    }
    __syncthreads();
    short* op = out + (size_t)l * 2304 * DM + (size_t)(p * DM + h * 64) * DM;
    #pragma unroll
    for (int it = 0; it < 2; it++){
      int e = it * 32 + (tid >> 3);
      int kc = (tid & 7) * 8;
      bf16x8 v;
      #pragma unroll
      for (int u = 0; u < 8; u++) v[u] = sh[kc + u][e];
      *(bf16x8*)(op + (size_t)e * DM + kt * 64 + kc) = v;
    }
  }
}

// ---------------- MFMA GEMM v9: depth-D prefetch LDS pipeline ---------------
// A,B^T via gl16+XOR swizzle, counted vmcnt (never 0 in steady state).
// Per-layer modes DEPTH=2 (3 buffers); LM DEPTH=1 (round-9-verified).
// MODE 0: QKV fused -> q,k [head][T][64] bf16; v transposed vt[head][64][T]
// MODE 1: MLP1 -> bf16 gelu(acc+bias)
// MODE 2: MLP2 single-z -> h += acc + bias (one writer per element, no split)
// MODE 3: LM XCD-pinned panels -> fp32 out (plain stores; NT falsified r13)
template<int MODE, int FI, int FJ>
__global__ __launch_bounds__(256) void mg_k(
    const short* __restrict__ A, const short* __restrict__ Bt,
    const float* __restrict__ b0, const float* __restrict__ b1,
    const float* __restrict__ b2,
    void* __restrict__ C0, void* __restrict__ C1, void* __restrict__ C2)
{
  constexpr int LDA    = (MODE == 2) ? DF_ : DM;
  constexpr int BM     = FI * 32;
  constexpr int BN     = FJ * 32;
  constexpr int ABYTES = BM * 64 * 2;
  constexpr int BBYTES = BN * 64 * 2;
  constexpr int TBYTES = ABYTES + BBYTES;
  constexpr int DEPTH  = (MODE == 3) ? 1 : 2;
  constexpr int NBUF   = DEPTH + 1;
  constexpr int W      = FI + FJ;            // VMEM instrs per stage per wave
  __shared__ __align__(16) char lds[NBUF * TBYTES];

  int tid = threadIdx.x;
  int wid = tid >> 6, lane = tid & 63;
  int l15 = lane & 15, l4 = lane >> 4;
  int wr = wid >> 1, wc = wid & 1;

  int m0, n0;
  if (MODE == 3){
    int xcd = blockIdx.x & 7, slot = blockIdx.x >> 3;
    int nb = xcd + 8 * (slot >> 3);
    if (nb >= NPAN) return;
    m0 = (slot & 7) * BM;
    n0 = nb * BN;
  } else {
    m0 = blockIdx.x * BM;
    n0 = blockIdx.y * BN;
  }
  int kbeg = 0;
  int nk   = LDA / 64;                       // 12 (DM) or 48 (DF_)

  f32x4 acc[FI][FJ] = {};
  int wbase = (tid & ~63) * 16;

  auto stage = [&](int k0, int b){
    char* ab = lds + b * TBYTES;
    char* bb = ab + ABYTES;
    #pragma unroll
    for (int ia = 0; ia < FI; ia++){
      int d = ia * 256 + tid;
      int row = d >> 3, gs = (d & 7) ^ (row & 7);
      gl16(A + (size_t)(m0 + row) * LDA + k0 + gs * 8, ab + ia * 4096 + wbase);
    }
    #pragma unroll
    for (int ib = 0; ib < FJ; ib++){
      int d = ib * 256 + tid;
      int row = d >> 3, gs = (d & 7) ^ (row & 7);
      gl16(Bt + (size_t)(n0 + row) * LDA + k0 + gs * 8, bb + ib * 4096 + wbase);
    }
  };

  // prologue: fill DEPTH tiles
  #pragma unroll
  for (int d = 0; d < DEPTH; d++)
    if (d < nk) stage(kbeg + d * 64, d);

  int cb = 0;                          // compute buffer
  int sb = DEPTH % NBUF;               // next stage buffer
  for (int t = 0; t < nk; ++t){
    if (t + DEPTH < nk){
      stage(kbeg + (t + DEPTH) * 64, sb);
      sb = (sb + 1 == NBUF) ? 0 : sb + 1;
      if constexpr (DEPTH * W == 4)       asm volatile("s_waitcnt vmcnt(4)"  ::: "memory");
      else if constexpr (DEPTH * W == 8)  asm volatile("s_waitcnt vmcnt(8)"  ::: "memory");
      else                                asm volatile("s_waitcnt vmcnt(16)" ::: "memory");
    } else if (DEPTH == 2 && t + 1 < nk){
      if constexpr (W == 4) asm volatile("s_waitcnt vmcnt(4)" ::: "memory");
      else                  asm volatile("s_waitcnt vmcnt(8)" ::: "memory");
    } else {
      asm volatile("s_waitcnt vmcnt(0)" ::: "memory");
    }
    __builtin_amdgcn_s_barrier();
    __builtin_amdgcn_sched_barrier(0);

    char* ab = lds + cb * TBYTES;
    char* bb = ab + ABYTES;
    cb = (cb + 1 == NBUF) ? 0 : cb + 1;
    #pragma unroll
    for (int kk = 0; kk < 2; kk++){
      bf16x8 af[FI], bfr[FJ];
      #pragma unroll
      for (int i = 0; i < FI; i++){
        int row = wr * (FI * 16) + i * 16 + l15;
        af[i] = *(const bf16x8*)(ab + row * 128 + (((kk * 4 + l4) ^ (row & 7)) * 16));
      }
      #pragma unroll
      for (int j = 0; j < FJ; j++){
        int row = wc * (FJ * 16) + j * 16 + l15;
        bfr[j] = *(const bf16x8*)(bb + row * 128 + (((kk * 4 + l4) ^ (row & 7)) * 16));
      }
      #pragma unroll
      for (int i = 0; i < FI; i++)
        #pragma unroll
        for (int j = 0; j < FJ; j++)
          acc[i][j] = __builtin_amdgcn_mfma_f32_16x16x32_bf16(af[i], bfr[j], acc[i][j], 0, 0, 0);
    }
    __builtin_amdgcn_sched_barrier(0);
    __builtin_amdgcn_s_barrier();
  }

  #pragma unroll
  for (int i = 0; i < FI; i++){
    int rowb = m0 + wr * (FI * 16) + i * 16 + l4 * 4;
    #pragma unroll
    for (int j = 0; j < FJ; j++){
      int col = n0 + wc * (FJ * 16) + j * 16 + l15;
      if (MODE == 0){
        int p = col / DM, within = col - p * DM;
        const float* bp = (p == 0) ? b0 : (p == 1) ? b1 : b2;
        float bb2 = bp[within];
        int hd = within >> 6, e = within & 63;
        if (p < 2){
          short* dst = (short*)((p == 0) ? C0 : C1);
          #pragma unroll
          for (int r = 0; r < 4; r++)
            dst[((size_t)hd * TLEN + rowb + r) * 64 + e] = f2bf(acc[i][j][r] + bb2);
        } else {
          short4 pk;
          pk.x = f2bf(acc[i][j][0] + bb2); pk.y = f2bf(acc[i][j][1] + bb2);
          pk.z = f2bf(acc[i][j][2] + bb2); pk.w = f2bf(acc[i][j][3] + bb2);
          *(short4*)((short*)C2 + ((size_t)hd * 64 + e) * TLEN + rowb) = pk;
        }
      } else if (MODE == 1){
        #pragma unroll
        for (int r = 0; r < 4; r++)
          ((short*)C0)[(size_t)(rowb + r) * DF_ + col] =
              f2bf(gelu_exact(acc[i][j][r] + b0[col]));
      } else if (MODE == 2){
        // residual accumulate: single writer per element (no split-K)
        float* dst = (float*)C0;
        float bb2 = b0[col];
        #pragma unroll
        for (int r = 0; r < 4; r++){
          size_t idx = (size_t)(rowb + r) * DM + col;
          dst[idx] = dst[idx] + acc[i][j][r] + bb2;
        }
      } else {
        if (col < VC){
          #pragma unroll
          for (int r = 0; r < 4; r++)
            ((float*)C0)[(size_t)(rowb + r) * VC + col] = acc[i][j][r];
        }
      }
    }
  }
}

// ---------------- MFMA flash attention (unchanged, passing) -----------------
__global__ __launch_bounds__(256) void attn_k(const short* __restrict__ q,
    const short* __restrict__ k, const short* __restrict__ vt,
    float* __restrict__ h)
{
  __shared__ short P_lds[4][16][72];
  int tid = threadIdx.x;
  int wid = tid >> 6, lane = tid & 63;
  int l15 = lane & 15, l4 = lane >> 4;
  int head = blockIdx.x >> 4, qt = blockIdx.x & 15;
  int qb = qt * 64 + wid * 16;

  const short* qh = q  + (size_t)head * TLEN * 64;
  const short* kh = k  + (size_t)head * TLEN * 64;
  const short* vh = vt + (size_t)head * 64 * TLEN;

  bf16x8 qf[2];
  qf[0] = *(const bf16x8*)(qh + (size_t)(qb + l15) * 64 + l4 * 8);
  qf[1] = *(const bf16x8*)(qh + (size_t)(qb + l15) * 64 + 32 + l4 * 8);

  f32x4 O[4] = {};
  float mrow[4] = {-3e38f, -3e38f, -3e38f, -3e38f};
  float lrow[4] = {0.f, 0.f, 0.f, 0.f};

  for (int kv0 = 0; kv0 <= qb + 15; kv0 += 64){
    f32x4 S[4] = {};
    #pragma unroll
    for (int kk = 0; kk < 2; kk++){
      #pragma unroll
      for (int j = 0; j < 4; j++){
        bf16x8 kf = *(const bf16x8*)(kh + (size_t)(kv0 + j*16 + l15) * 64
                                     + kk*32 + l4*8);
        S[j] = __builtin_amdgcn_mfma_f32_16x16x32_bf16(qf[kk], kf, S[j], 0, 0, 0);
      }
    }
    if (kv0 + 63 > qb){
      #pragma unroll
      for (int j = 0; j < 4; j++){
        int kvc = kv0 + j*16 + l15;
        #pragma unroll
        for (int r = 0; r < 4; r++)
          if (kvc > qb + l4*4 + r) S[j][r] = -3e38f;
      }
    }
    #pragma unroll
    for (int r = 0; r < 4; r++){
      float mx = fmaxf(fmaxf(S[0][r], S[1][r]), fmaxf(S[2][r], S[3][r]));
      #pragma unroll
      for (int off = 1; off < 16; off <<= 1) mx = fmaxf(mx, __shfl_xor(mx, off));
      float mn = fmaxf(mrow[r], mx);
      float corr = __expf(mrow[r] - mn);
      mrow[r] = mn;
      float sm = 0.f;
      #pragma unroll
      for (int j = 0; j < 4; j++){
        float p = __expf(S[j][r] - mn);
        S[j][r] = p; sm += p;
      }
      #pragma unroll
      for (int off = 1; off < 16; off <<= 1) sm += __shfl_xor(sm, off);
      lrow[r] = lrow[r] * corr + sm;
      #pragma unroll
      for (int j = 0; j < 4; j++) O[j][r] *= corr;
    }
    #pragma unroll
    for (int j = 0; j < 4; j++)
      #pragma unroll
      for (int r = 0; r < 4; r++)
        P_lds[wid][l4*4 + r][j*16 + l15] = f2bf(S[j][r]);
    #pragma unroll
    for (int kk = 0; kk < 2; kk++){
      bf16x8 pa = *(const bf16x8*)(&P_lds[wid][l15][kk*32 + l4*8]);
      #pragma unroll
      for (int jd = 0; jd < 4; jd++){
        bf16x8 vf = *(const bf16x8*)(vh + (size_t)(jd*16 + l15) * TLEN
                                     + kv0 + kk*32 + l4*8);
        O[jd] = __builtin_amdgcn_mfma_f32_16x16x32_bf16(pa, vf, O[jd], 0, 0, 0);
      }
    }
  }

  #pragma unroll
  for (int r = 0; r < 4; r++){
    float inv = 1.0f / lrow[r];
    int t = qb + l4*4 + r;
    #pragma unroll
    for (int jd = 0; jd < 4; jd++){
      int d = head * 64 + jd*16 + l15;
      h[(size_t)t * DM + d] += O[jd][r] * inv;
    }
  }
}

extern "C" void kernel_launch(void* const* d_in, const int* in_sizes, int n_in,
                              void* d_out, int out_size, void* d_ws, size_t ws_size,
                              hipStream_t stream)
{
  const int*   x    = (const int*)  d_in[0];
  const float* wte  = (const float*)d_in[1];
  const float* wpe  = (const float*)d_in[2];
  const float* Wq   = (const float*)d_in[3];
  const float* bq   = (const float*)d_in[4];
  const float* Wk   = (const float*)d_in[5];
  const float* bk   = (const float*)d_in[6];
  const float* Wv   = (const float*)d_in[7];
  const float* bv   = (const float*)d_in[8];
  const float* ln1s = (const float*)d_in[9];
  const float* ln1b = (const float*)d_in[10];
  const float* W1   = (const float*)d_in[11];
  const float* b1   = (const float*)d_in[12];
  const float* W2   = (const float*)d_in[13];
  const float* b2   = (const float*)d_in[14];
  const float* ln2s = (const float*)d_in[15];
  const float* ln2b = (const float*)d_in[16];
  const float* lnfs = (const float*)d_in[17];
  const float* lnfb = (const float*)d_in[18];
  const float* Wlm  = (const float*)d_in[19];
  float* out = (float*)d_out;

  const size_t SZ_QKVT = (size_t)NL * 2304 * DM * 2;
  const size_t SZ_W1T  = (size_t)NL * DF_ * DM * 2;
  const size_t SZ_W2T  = (size_t)NL * DM * DF_ * 2;
  const size_t SZ_WLMT = (size_t)VCP * DM * 2;
  const size_t SZ_H    = (size_t)TLEN * DM * 4;   // fp32 h
  const size_t SZ_BF   = (size_t)TLEN * DM * 2;   // bf16 activation

  char* ws = (char*)d_ws;
  short* wqkvT = (short*)ws;  ws += SZ_QKVT;
  short* w1T   = (short*)ws;  ws += SZ_W1T;
  short* w2T   = (short*)ws;  ws += SZ_W2T;
  short* wlmT  = (short*)ws;  ws += SZ_WLMT;
  float* h     = (float*)ws;  ws += SZ_H;
  short* qb    = (short*)ws;  ws += SZ_BF;
  short* kb    = (short*)ws;  ws += SZ_BF;
  short* vtb   = (short*)ws;  ws += SZ_BF;
  short* xnb   = (short*)ws;  ws += SZ_BF;
  short* mhb   = (short*)ws;

  tcqkv_k<<<NL*NH*12, 256, 0, stream>>>(Wq, Wk, Wv, wqkvT);
  tc_k<<<NL*48*12, 256, 0, stream>>>(W1, w1T, DM, DF_, 48, 576,
                                     (size_t)DM*DF_, (size_t)DM*DF_);
  tc_k<<<NL*12*48, 256, 0, stream>>>(W2, w2T, DF_, DM, 12, 576,
                                     (size_t)DM*DF_, (size_t)DM*DF_);
  tc_k<<<786*12, 256, 0, stream>>>(Wlm, wlmT, DM, VC, 786, 786*12, 0, 0);

  embedln_k<<<TLEN/4, 256, 0, stream>>>(x, wte, wpe, ln1s, ln1b, h, xnb);

  for (int l = 0; l < NL; ++l){
    mg_k<0,2,2><<<dim3(16,36), 256, 0, stream>>>(xnb, wqkvT + (size_t)l*2304*DM,
        bq + l*DM, bk + l*DM, bv + l*DM, qb, kb, vtb);
    attn_k<<<NH*16, 256, 0, stream>>>(qb, kb, vtb, h);
    ln_k<<<TLEN/4, 256, 0, stream>>>(h, ln2s + l*DM, ln2b + l*DM, xnb);
    mg_k<1,2,2><<<dim3(16,48), 256, 0, stream>>>(xnb, w1T + (size_t)l*DF_*DM,
        b1 + l*DF_, nullptr, nullptr, mhb, nullptr, nullptr);
    // MLP2: single-z, direct residual accumulate into h (no partials)
    mg_k<2,2,2><<<dim3(16,12), 256, 0, stream>>>(mhb, w2T + (size_t)l*DM*DF_,
        b2 + l*DM, nullptr, nullptr, h, nullptr, nullptr);
    const float* nsc = (l < NL-1) ? ln1s + (l+1)*DM : lnfs;
    const float* nbi = (l < NL-1) ? ln1b + (l+1)*DM : lnfb;
    ln_k<<<TLEN/4, 256, 0, stream>>>(h, nsc, nbi, xnb);
  }

  // LM head: round-9-verified 128x128 XCD-pinned grid, depth-1, plain stores
  mg_k<3,4,4><<<3200, 256, 0, stream>>>(xnb, wlmT,
      nullptr, nullptr, nullptr, out, nullptr, nullptr);
}

// Round 16
// 1302.810 us; speedup vs baseline: 1.0060x; 1.0060x over previous
//
#include <hip/hip_runtime.h>
#include <math.h>

#define TLEN 1024
#define DM   768
#define NH   12
#define HSZ  64
#define DF_  3072
#define NL   12
#define VC   50257
#define VCP  50304          // VC padded to 64
#define NPAN (VCP/128)      // 393 LM N-panels

typedef __attribute__((ext_vector_type(8))) short bf16x8;
typedef __attribute__((ext_vector_type(4))) float f32x4;

__device__ __forceinline__ float gelu_exact(float x){
  return 0.5f * x * (1.0f + erff(x * 0.70710678118654752f));
}
__device__ __forceinline__ short f2bf(float f){
  union { float f; unsigned u; } x; x.f = f;
  unsigned r = x.u + 0x7fffu + ((x.u >> 16) & 1u);
  return (short)(r >> 16);
}
__device__ __forceinline__ void gl16(const void* g, void* l){
  __builtin_amdgcn_global_load_lds(
      (const __attribute__((address_space(1))) unsigned int*)g,
      (__attribute__((address_space(3))) unsigned int*)l, 16, 0, 0);
}

// ---------------- embedding fused with layer-0 ln1: wave per row ------------
__global__ __launch_bounds__(256) void embedln_k(const int* __restrict__ x,
    const float* __restrict__ wte, const float* __restrict__ wpe,
    const float* __restrict__ sc, const float* __restrict__ bi,
    float* __restrict__ h, short* __restrict__ out)
{
  int w = threadIdx.x >> 6, lane = threadIdx.x & 63;
  int t = blockIdx.x * 4 + w;
  int tok = x[t];
  size_t off = (size_t)t * DM;
  float v[12];
  float s = 0.f, s2 = 0.f;
  #pragma unroll
  for (int i = 0; i < 12; i++){
    int c = lane + i * 64;
    float xv = wte[(size_t)tok * DM + c] + wpe[off + c];
    h[off + c] = xv;
    v[i] = xv; s += xv; s2 += xv * xv;
  }
  #pragma unroll
  for (int o = 32; o; o >>= 1){ s += __shfl_xor(s, o); s2 += __shfl_xor(s2, o); }
  float mu = s * (1.0f / DM);
  float var = s2 * (1.0f / DM) - mu * mu;
  float rs = rsqrtf(var + 1e-5f);
  #pragma unroll
  for (int i = 0; i < 12; i++){
    int c = lane + i * 64;
    out[off + c] = f2bf((v[i] - mu) * rs * sc[c] + bi[c]);
  }
}

// ---------------- layernorm: fp32 in, bf16 out (used for ln2) ---------------
__global__ __launch_bounds__(256) void ln_k(const float* __restrict__ in,
    const float* __restrict__ sc, const float* __restrict__ bi,
    short* __restrict__ out)
{
  int w = threadIdx.x >> 6, lane = threadIdx.x & 63;
  int row = blockIdx.x * 4 + w;
  const float* r = in + (size_t)row * DM;
  float v[12];
  float s = 0.f, s2 = 0.f;
  #pragma unroll
  for (int i = 0; i < 12; i++){
    float xv = r[lane + i * 64];
    v[i] = xv; s += xv; s2 += xv * xv;
  }
  #pragma unroll
  for (int o = 32; o; o >>= 1){ s += __shfl_xor(s, o); s2 += __shfl_xor(s2, o); }
  float mu  = s * (1.0f / DM);
  float var = s2 * (1.0f / DM) - mu * mu;
  float rs  = rsqrtf(var + 1e-5f);
  short* o = out + (size_t)row * DM;
  #pragma unroll
  for (int i = 0; i < 12; i++){
    int c = lane + i * 64;
    o[c] = f2bf((v[i] - mu) * rs * sc[c] + bi[c]);
  }
}

// ---- split-K reduce + residual + bias + NEXT-layer LN, wave per row --------
__global__ __launch_bounds__(256) void redln_k(float* __restrict__ h,
    const float* __restrict__ p0, const float* __restrict__ p1,
    const float* __restrict__ bias,
    const float* __restrict__ sc, const float* __restrict__ bi,
    short* __restrict__ out)
{
  int w = threadIdx.x >> 6, lane = threadIdx.x & 63;
  int row = blockIdx.x * 4 + w;
  size_t off = (size_t)row * DM;
  float v[12];
  float s = 0.f, s2 = 0.f;
  #pragma unroll
  for (int i = 0; i < 12; i++){
    int c = lane + i * 64;
    float xv = h[off + c] + p0[off + c] + p1[off + c] + bias[c];
    h[off + c] = xv;
    v[i] = xv; s += xv; s2 += xv * xv;
  }
  #pragma unroll
  for (int o = 32; o; o >>= 1){ s += __shfl_xor(s, o); s2 += __shfl_xor(s2, o); }
  float mu  = s * (1.0f / DM);
  float var = s2 * (1.0f / DM) - mu * mu;
  float rs  = rsqrtf(var + 1e-5f);
  #pragma unroll
  for (int i = 0; i < 12; i++){
    int c = lane + i * 64;
    out[off + c] = f2bf((v[i] - mu) * rs * sc[c] + bi[c]);
  }
}

// ---------------- transpose-cast: W [K][N] f32 -> WT [Nt*64][K] bf16 --------
__global__ __launch_bounds__(256) void tc_k(const float* __restrict__ in,
    short* __restrict__ out, int K, int N, int ntiles, int per_mat,
    size_t in_stride, size_t out_stride)
{
  __shared__ short sh[64][65];
  int b = blockIdx.x;
  int l = b / per_mat, r = b - l * per_mat;
  int nt = r % ntiles, kt = r / ntiles;
  const float* ip = in + (size_t)l * in_stride;
  short* op = out + (size_t)l * out_stride;
  int n0 = nt * 64, k0 = kt * 64;
  int tid = threadIdx.x;
  if ((N & 3) == 0){
    #pragma unroll
    for (int it = 0; it < 4; it++){
      int idx = it * 256 + tid;
      int k = idx >> 4, n4 = (idx & 15) * 4;
      float4 v = *(const float4*)(ip + (size_t)(k0 + k) * N + n0 + n4);
      sh[k][n4+0] = f2bf(v.x); sh[k][n4+1] = f2bf(v.y);
      sh[k][n4+2] = f2bf(v.z); sh[k][n4+3] = f2bf(v.w);
    }
  } else {
    #pragma unroll
    for (int it = 0; it < 16; it++){
      int idx = it * 256 + tid;
      int k = idx >> 6, n = idx & 63;
      float v = (n0 + n < N) ? ip[(size_t)(k0 + k) * N + n0 + n] : 0.f;
      sh[k][n] = f2bf(v);
    }
  }
  __syncthreads();
  #pragma unroll
  for (int it = 0; it < 2; it++){
    int n = it * 32 + (tid >> 3);
    int kc = (tid & 7) * 8;
    bf16x8 v;
    #pragma unroll
    for (int u = 0; u < 8; u++) v[u] = sh[kc + u][n];
    *(bf16x8*)(op + (size_t)(n0 + n) * K + k0 + kc) = v;
  }
}

// ---------------- QKV transpose-cast: [L][H][768][64] x3 -> [L][2304][768] --
__global__ __launch_bounds__(256) void tcqkv_k(const float* __restrict__ Wq,
    const float* __restrict__ Wk, const float* __restrict__ Wv,
    short* __restrict__ out)
{
  __shared__ short sh[64][65];
  int b = blockIdx.x;            // L*H*12
  int l = b / 144; int r = b - l * 144;
  int h = r / 12, kt = r - h * 12;
  int tid = threadIdx.x;
  for (int p = 0; p < 3; p++){
    const float* ip = (p == 0 ? Wq : p == 1 ? Wk : Wv)
                      + ((size_t)(l * NH + h) * DM + kt * 64) * 64;
    if (p) __syncthreads();
    #pragma unroll
    for (int it = 0; it < 4; it++){
      int idx = it * 256 + tid;
      int k = idx >> 4, e4 = (idx & 15) * 4;
      float4 v = *(const float4*)(ip + (size_t)k * 64 + e4);
      sh[k][e4+0] = f2bf(v.x); sh[k][e4+1] = f2bf(v.y);
      sh[k][e4+2] = f2bf(v.z); sh[k][e4+3] = f2bf(v.w);
    }
    __syncthreads();
    short* op = out + (size_t)l * 2304 * DM + (size_t)(p * DM + h * 64) * DM;
    #pragma unroll
    for (int it = 0; it < 2; it++){
      int e = it * 32 + (tid >> 3);
      int kc = (tid & 7) * 8;
      bf16x8 v;
      #pragma unroll
      for (int u = 0; u < 8; u++) v[u] = sh[kc + u][e];
      *(bf16x8*)(op + (size_t)e * DM + kt * 64 + kc) = v;
    }
  }
}

// ---------------- MFMA GEMM v10: depth-D pipeline, parametric BK ------------
// A,B^T via gl16+XOR swizzle, counted vmcnt (never 0 in steady state).
// Per-layer: BK=64, DEPTH=2 (byte-identical to round-14-verified paths).
// LM (MODE 3): BK=32, DEPTH=1 -> 32KB LDS -> 5 blocks/CU (LM is LDS-BW bound
// at 2 blocks/CU; more resident blocks saturate the LDS/MFMA pipes).
// Swizzle derivation: row of BK*2 bytes contributes ((row*BK*2/4)%32) to the
// bank index. BK=64: rows align to bank 0 -> XOR granule with (row&7) walks
// all 8 quads. BK=32: rows contribute (row&1)*16 -> XOR with ((row>>1)&3)
// so (row&1, swz) jointly walk all 8 quads; 16 rows -> 2-way (free, m136).
// Same involution applied on stage (global-side) and read (rule #21).
// MODE 0: QKV fused; MODE 1: MLP1 gelu; MODE 2: MLP2 split-K plain stores;
// MODE 3: LM XCD-pinned panels (plain stores; NT falsified r13).
template<int MODE, int FI, int FJ, int BK>
__global__ __launch_bounds__(256) void mg_k(
    const short* __restrict__ A, const short* __restrict__ Bt,
    const float* __restrict__ b0, const float* __restrict__ b1,
    const float* __restrict__ b2,
    void* __restrict__ C0, void* __restrict__ C1, void* __restrict__ C2)
{
  constexpr int LDA    = (MODE == 2) ? DF_ : DM;
  constexpr int BM     = FI * 32;
  constexpr int BN     = FJ * 32;
  constexpr int ABYTES = BM * BK * 2;
  constexpr int BBYTES = BN * BK * 2;
  constexpr int TBYTES = ABYTES + BBYTES;
  constexpr int DEPTH  = (MODE == 3) ? 1 : 2;
  constexpr int NBUF   = DEPTH + 1;
  constexpr int GR     = BK / 8;             // 16B granules per LDS row
  constexpr int NCHA   = ABYTES / 4096;      // gl16 chunks for A
  constexpr int NCHB   = BBYTES / 4096;
  constexpr int W      = NCHA + NCHB;        // VMEM instrs per stage per wave
  __shared__ __align__(16) char lds[NBUF * TBYTES];

  int tid = threadIdx.x;
  int wid = tid >> 6, lane = tid & 63;
  int l15 = lane & 15, l4 = lane >> 4;
  int wr = wid >> 1, wc = wid & 1;

  int m0, n0;
  if (MODE == 3){
    int xcd = blockIdx.x & 7, slot = blockIdx.x >> 3;
    int nb = xcd + 8 * (slot >> 3);
    if (nb >= NPAN) return;
    m0 = (slot & 7) * BM;
    n0 = nb * BN;
  } else {
    m0 = blockIdx.x * BM;
    n0 = blockIdx.y * BN;
  }
  int kbeg = (MODE == 2) ? blockIdx.z * (DF_ / 2) : 0;
  int nk   = ((MODE == 2) ? DF_ / 2 : LDA) / BK;

  f32x4 acc[FI][FJ] = {};
  int wbase = (tid & ~63) * 16;

  auto stage = [&](int k0, int b){
    char* ab = lds + b * TBYTES;
    char* bb = ab + ABYTES;
    #pragma unroll
    for (int ia = 0; ia < NCHA; ia++){
      int d = ia * 256 + tid;
      int row = d / GR, g = d & (GR - 1);
      int gs;
      if constexpr (BK == 64) gs = g ^ (row & 7);
      else                    gs = g ^ ((row >> 1) & 3);
      gl16(A + (size_t)(m0 + row) * LDA + k0 + gs * 8, ab + ia * 4096 + wbase);
    }
    #pragma unroll
    for (int ib = 0; ib < NCHB; ib++){
      int d = ib * 256 + tid;
      int row = d / GR, g = d & (GR - 1);
      int gs;
      if constexpr (BK == 64) gs = g ^ (row & 7);
      else                    gs = g ^ ((row >> 1) & 3);
      gl16(Bt + (size_t)(n0 + row) * LDA + k0 + gs * 8, bb + ib * 4096 + wbase);
    }
  };

  // prologue: fill DEPTH tiles
  #pragma unroll
  for (int d = 0; d < DEPTH; d++)
    if (d < nk) stage(kbeg + d * BK, d);

  int cb = 0;                          // compute buffer
  int sb = DEPTH % NBUF;               // next stage buffer
  for (int t = 0; t < nk; ++t){
    if (t + DEPTH < nk){
      stage(kbeg + (t + DEPTH) * BK, sb);
      sb = (sb + 1 == NBUF) ? 0 : sb + 1;
      if constexpr (DEPTH * W == 4)       asm volatile("s_waitcnt vmcnt(4)"  ::: "memory");
      else if constexpr (DEPTH * W == 8)  asm volatile("s_waitcnt vmcnt(8)"  ::: "memory");
      else                                asm volatile("s_waitcnt vmcnt(16)" ::: "memory");
    } else if (DEPTH == 2 && t + 1 < nk){
      if constexpr (W == 4) asm volatile("s_waitcnt vmcnt(4)" ::: "memory");
      else                  asm volatile("s_waitcnt vmcnt(8)" ::: "memory");
    } else {
      asm volatile("s_waitcnt vmcnt(0)" ::: "memory");
    }
    __builtin_amdgcn_s_barrier();
    __builtin_amdgcn_sched_barrier(0);

    char* ab = lds + cb * TBYTES;
    char* bb = ab + ABYTES;
    cb = (cb + 1 == NBUF) ? 0 : cb + 1;
    #pragma unroll
    for (int kk = 0; kk < BK / 32; kk++){
      bf16x8 af[FI], bfr[FJ];
      #pragma unroll
      for (int i = 0; i < FI; i++){
        int row = wr * (FI * 16) + i * 16 + l15;
        int swz;
        if constexpr (BK == 64) swz = (kk * 4 + l4) ^ (row & 7);
        else                    swz = l4 ^ ((row >> 1) & 3);
        af[i] = *(const bf16x8*)(ab + row * (BK * 2) + swz * 16);
      }
      #pragma unroll
      for (int j = 0; j < FJ; j++){
        int row = wc * (FJ * 16) + j * 16 + l15;
        int swz;
        if constexpr (BK == 64) swz = (kk * 4 + l4) ^ (row & 7);
        else                    swz = l4 ^ ((row >> 1) & 3);
        bfr[j] = *(const bf16x8*)(bb + row * (BK * 2) + swz * 16);
      }
      #pragma unroll
      for (int i = 0; i < FI; i++)
        #pragma unroll
        for (int j = 0; j < FJ; j++)
          acc[i][j] = __builtin_amdgcn_mfma_f32_16x16x32_bf16(af[i], bfr[j], acc[i][j], 0, 0, 0);
    }
    __builtin_amdgcn_sched_barrier(0);
    __builtin_amdgcn_s_barrier();
  }

  #pragma unroll
  for (int i = 0; i < FI; i++){
    int rowb = m0 + wr * (FI * 16) + i * 16 + l4 * 4;
    #pragma unroll
    for (int j = 0; j < FJ; j++){
      int col = n0 + wc * (FJ * 16) + j * 16 + l15;
      if (MODE == 0){
        int p = col / DM, within = col - p * DM;
        const float* bp = (p == 0) ? b0 : (p == 1) ? b1 : b2;
        float bb2 = bp[within];
        int hd = within >> 6, e = within & 63;
        if (p < 2){
          short* dst = (short*)((p == 0) ? C0 : C1);
          #pragma unroll
          for (int r = 0; r < 4; r++)
            dst[((size_t)hd * TLEN + rowb + r) * 64 + e] = f2bf(acc[i][j][r] + bb2);
        } else {
          short4 pk;
          pk.x = f2bf(acc[i][j][0] + bb2); pk.y = f2bf(acc[i][j][1] + bb2);
          pk.z = f2bf(acc[i][j][2] + bb2); pk.w = f2bf(acc[i][j][3] + bb2);
          *(short4*)((short*)C2 + ((size_t)hd * 64 + e) * TLEN + rowb) = pk;
        }
      } else if (MODE == 1){
        #pragma unroll
        for (int r = 0; r < 4; r++)
          ((short*)C0)[(size_t)(rowb + r) * DF_ + col] =
              f2bf(gelu_exact(acc[i][j][r] + b0[col]));
      } else if (MODE == 2){
        float* dst = (float*)((blockIdx.z == 0) ? C0 : C1);
        #pragma unroll
        for (int r = 0; r < 4; r++)
          dst[(size_t)(rowb + r) * DM + col] = acc[i][j][r];
      } else {
        if (col < VC){
          #pragma unroll
          for (int r = 0; r < 4; r++)
            ((float*)C0)[(size_t)(rowb + r) * VC + col] = acc[i][j][r];
        }
      }
    }
  }
}

// ---------------- MFMA flash attention (unchanged, passing) -----------------
__global__ __launch_bounds__(256) void attn_k(const short* __restrict__ q,
    const short* __restrict__ k, const short* __restrict__ vt,
    float* __restrict__ h)
{
  __shared__ short P_lds[4][16][72];
  int tid = threadIdx.x;
  int wid = tid >> 6, lane = tid & 63;
  int l15 = lane & 15, l4 = lane >> 4;
  int head = blockIdx.x >> 4, qt = blockIdx.x & 15;
  int qb = qt * 64 + wid * 16;

  const short* qh = q  + (size_t)head * TLEN * 64;
  const short* kh = k  + (size_t)head * TLEN * 64;
  const short* vh = vt + (size_t)head * 64 * TLEN;

  bf16x8 qf[2];
  qf[0] = *(const bf16x8*)(qh + (size_t)(qb + l15) * 64 + l4 * 8);
  qf[1] = *(const bf16x8*)(qh + (size_t)(qb + l15) * 64 + 32 + l4 * 8);

  f32x4 O[4] = {};
  float mrow[4] = {-3e38f, -3e38f, -3e38f, -3e38f};
  float lrow[4] = {0.f, 0.f, 0.f, 0.f};

  for (int kv0 = 0; kv0 <= qb + 15; kv0 += 64){
    f32x4 S[4] = {};
    #pragma unroll
    for (int kk = 0; kk < 2; kk++){
      #pragma unroll
      for (int j = 0; j < 4; j++){
        bf16x8 kf = *(const bf16x8*)(kh + (size_t)(kv0 + j*16 + l15) * 64
                                     + kk*32 + l4*8);
        S[j] = __builtin_amdgcn_mfma_f32_16x16x32_bf16(qf[kk], kf, S[j], 0, 0, 0);
      }
    }
    if (kv0 + 63 > qb){
      #pragma unroll
      for (int j = 0; j < 4; j++){
        int kvc = kv0 + j*16 + l15;
        #pragma unroll
        for (int r = 0; r < 4; r++)
          if (kvc > qb + l4*4 + r) S[j][r] = -3e38f;
      }
    }
    #pragma unroll
    for (int r = 0; r < 4; r++){
      float mx = fmaxf(fmaxf(S[0][r], S[1][r]), fmaxf(S[2][r], S[3][r]));
      #pragma unroll
      for (int off = 1; off < 16; off <<= 1) mx = fmaxf(mx, __shfl_xor(mx, off));
      float mn = fmaxf(mrow[r], mx);
      float corr = __expf(mrow[r] - mn);
      mrow[r] = mn;
      float sm = 0.f;
      #pragma unroll
      for (int j = 0; j < 4; j++){
        float p = __expf(S[j][r] - mn);
        S[j][r] = p; sm += p;
      }
      #pragma unroll
      for (int off = 1; off < 16; off <<= 1) sm += __shfl_xor(sm, off);
      lrow[r] = lrow[r] * corr + sm;
      #pragma unroll
      for (int j = 0; j < 4; j++) O[j][r] *= corr;
    }
    #pragma unroll
    for (int j = 0; j < 4; j++)
      #pragma unroll
      for (int r = 0; r < 4; r++)
        P_lds[wid][l4*4 + r][j*16 + l15] = f2bf(S[j][r]);
    #pragma unroll
    for (int kk = 0; kk < 2; kk++){
      bf16x8 pa = *(const bf16x8*)(&P_lds[wid][l15][kk*32 + l4*8]);
      #pragma unroll
      for (int jd = 0; jd < 4; jd++){
        bf16x8 vf = *(const bf16x8*)(vh + (size_t)(jd*16 + l15) * TLEN
                                     + kv0 + kk*32 + l4*8);
        O[jd] = __builtin_amdgcn_mfma_f32_16x16x32_bf16(pa, vf, O[jd], 0, 0, 0);
      }
    }
  }

  #pragma unroll
  for (int r = 0; r < 4; r++){
    float inv = 1.0f / lrow[r];
    int t = qb + l4*4 + r;
    #pragma unroll
    for (int jd = 0; jd < 4; jd++){
      int d = head * 64 + jd*16 + l15;
      h[(size_t)t * DM + d] += O[jd][r] * inv;
    }
  }
}

extern "C" void kernel_launch(void* const* d_in, const int* in_sizes, int n_in,
                              void* d_out, int out_size, void* d_ws, size_t ws_size,
                              hipStream_t stream)
{
  const int*   x    = (const int*)  d_in[0];
  const float* wte  = (const float*)d_in[1];
  const float* wpe  = (const float*)d_in[2];
  const float* Wq   = (const float*)d_in[3];
  const float* bq   = (const float*)d_in[4];
  const float* Wk   = (const float*)d_in[5];
  const float* bk   = (const float*)d_in[6];
  const float* Wv   = (const float*)d_in[7];
  const float* bv   = (const float*)d_in[8];
  const float* ln1s = (const float*)d_in[9];
  const float* ln1b = (const float*)d_in[10];
  const float* W1   = (const float*)d_in[11];
  const float* b1   = (const float*)d_in[12];
  const float* W2   = (const float*)d_in[13];
  const float* b2   = (const float*)d_in[14];
  const float* ln2s = (const float*)d_in[15];
  const float* ln2b = (const float*)d_in[16];
  const float* lnfs = (const float*)d_in[17];
  const float* lnfb = (const float*)d_in[18];
  const float* Wlm  = (const float*)d_in[19];
  float* out = (float*)d_out;

  const size_t SZ_QKVT = (size_t)NL * 2304 * DM * 2;
  const size_t SZ_W1T  = (size_t)NL * DF_ * DM * 2;
  const size_t SZ_W2T  = (size_t)NL * DM * DF_ * 2;
  const size_t SZ_WLMT = (size_t)VCP * DM * 2;
  const size_t SZ_H    = (size_t)TLEN * DM * 4;   // fp32 h / partial
  const size_t SZ_BF   = (size_t)TLEN * DM * 2;   // bf16 activation

  char* ws = (char*)d_ws;
  short* wqkvT = (short*)ws;  ws += SZ_QKVT;
  short* w1T   = (short*)ws;  ws += SZ_W1T;
  short* w2T   = (short*)ws;  ws += SZ_W2T;
  short* wlmT  = (short*)ws;  ws += SZ_WLMT;
  float* h     = (float*)ws;  ws += SZ_H;
  short* qb    = (short*)ws;  ws += SZ_BF;
  short* kb    = (short*)ws;  ws += SZ_BF;
  short* vtb   = (short*)ws;  ws += SZ_BF;
  short* xnb   = (short*)ws;  ws += SZ_BF;
  short* mhb   = (short*)ws;  ws += (size_t)TLEN * DF_ * 2;
  float* p1    = (float*)ws;  // fresh 3 MB
  float* p0    = (float*)qb;  // overlays qb+kb (dead during MLP2/redln)

  tcqkv_k<<<NL*NH*12, 256, 0, stream>>>(Wq, Wk, Wv, wqkvT);
  tc_k<<<NL*48*12, 256, 0, stream>>>(W1, w1T, DM, DF_, 48, 576,
                                     (size_t)DM*DF_, (size_t)DM*DF_);
  tc_k<<<NL*12*48, 256, 0, stream>>>(W2, w2T, DF_, DM, 12, 576,
                                     (size_t)DM*DF_, (size_t)DM*DF_);
  tc_k<<<786*12, 256, 0, stream>>>(Wlm, wlmT, DM, VC, 786, 786*12, 0, 0);

  embedln_k<<<TLEN/4, 256, 0, stream>>>(x, wte, wpe, ln1s, ln1b, h, xnb);

  for (int l = 0; l < NL; ++l){
    mg_k<0,2,2,64><<<dim3(16,36), 256, 0, stream>>>(xnb, wqkvT + (size_t)l*2304*DM,
        bq + l*DM, bk + l*DM, bv + l*DM, qb, kb, vtb);
    attn_k<<<NH*16, 256, 0, stream>>>(qb, kb, vtb, h);
    ln_k<<<TLEN/4, 256, 0, stream>>>(h, ln2s + l*DM, ln2b + l*DM, xnb);
    mg_k<1,2,2,64><<<dim3(16,48), 256, 0, stream>>>(xnb, w1T + (size_t)l*DF_*DM,
        b1 + l*DF_, nullptr, nullptr, mhb, nullptr, nullptr);
    mg_k<2,2,2,64><<<dim3(16,12,2), 256, 0, stream>>>(mhb, w2T + (size_t)l*DM*DF_,
        nullptr, nullptr, nullptr, p0, p1, nullptr);
    const float* nsc = (l < NL-1) ? ln1s + (l+1)*DM : lnfs;
    const float* nbi = (l < NL-1) ? ln1b + (l+1)*DM : lnfb;
    redln_k<<<TLEN/4, 256, 0, stream>>>(h, p0, p1, b2 + l*DM, nsc, nbi, xnb);
  }

  // LM head: 128x128 XCD-pinned, BK=32 depth-1 -> 32KB LDS, 5 blocks/CU
  mg_k<3,4,4,32><<<3200, 256, 0, stream>>>(xnb, wlmT,
      nullptr, nullptr, nullptr, out, nullptr, nullptr);
}

// Round 17
// 1299.781 us; speedup vs baseline: 1.0083x; 1.0023x over previous
//
#include <hip/hip_runtime.h>
#include <math.h>

#define TLEN 1024
#define DM   768
#define NH   12
#define HSZ  64
#define DF_  3072
#define NL   12
#define VC   50257
#define VCP  50304          // VC padded to 64
#define NPAN (VCP/128)      // 393 LM N-panels

typedef __attribute__((ext_vector_type(8))) short bf16x8;
typedef __attribute__((ext_vector_type(4))) float f32x4;

__device__ __forceinline__ float gelu_exact(float x){
  return 0.5f * x * (1.0f + erff(x * 0.70710678118654752f));
}
__device__ __forceinline__ short f2bf(float f){
  union { float f; unsigned u; } x; x.f = f;
  unsigned r = x.u + 0x7fffu + ((x.u >> 16) & 1u);
  return (short)(r >> 16);
}
__device__ __forceinline__ void gl16(const void* g, void* l){
  __builtin_amdgcn_global_load_lds(
      (const __attribute__((address_space(1))) unsigned int*)g,
      (__attribute__((address_space(3))) unsigned int*)l, 16, 0, 0);
}

// ---------------- embedding fused with layer-0 ln1: wave per row ------------
__global__ __launch_bounds__(256) void embedln_k(const int* __restrict__ x,
    const float* __restrict__ wte, const float* __restrict__ wpe,
    const float* __restrict__ sc, const float* __restrict__ bi,
    float* __restrict__ h, short* __restrict__ out)
{
  int w = threadIdx.x >> 6, lane = threadIdx.x & 63;
  int t = blockIdx.x * 4 + w;
  int tok = x[t];
  size_t off = (size_t)t * DM;
  float v[12];
  float s = 0.f, s2 = 0.f;
  #pragma unroll
  for (int i = 0; i < 12; i++){
    int c = lane + i * 64;
    float xv = wte[(size_t)tok * DM + c] + wpe[off + c];
    h[off + c] = xv;
    v[i] = xv; s += xv; s2 += xv * xv;
  }
  #pragma unroll
  for (int o = 32; o; o >>= 1){ s += __shfl_xor(s, o); s2 += __shfl_xor(s2, o); }
  float mu = s * (1.0f / DM);
  float var = s2 * (1.0f / DM) - mu * mu;
  float rs = rsqrtf(var + 1e-5f);
  #pragma unroll
  for (int i = 0; i < 12; i++){
    int c = lane + i * 64;
    out[off + c] = f2bf((v[i] - mu) * rs * sc[c] + bi[c]);
  }
}

// ---------------- layernorm: fp32 in, bf16 out (used for ln2) ---------------
__global__ __launch_bounds__(256) void ln_k(const float* __restrict__ in,
    const float* __restrict__ sc, const float* __restrict__ bi,
    short* __restrict__ out)
{
  int w = threadIdx.x >> 6, lane = threadIdx.x & 63;
  int row = blockIdx.x * 4 + w;
  const float* r = in + (size_t)row * DM;
  float v[12];
  float s = 0.f, s2 = 0.f;
  #pragma unroll
  for (int i = 0; i < 12; i++){
    float xv = r[lane + i * 64];
    v[i] = xv; s += xv; s2 += xv * xv;
  }
  #pragma unroll
  for (int o = 32; o; o >>= 1){ s += __shfl_xor(s, o); s2 += __shfl_xor(s2, o); }
  float mu  = s * (1.0f / DM);
  float var = s2 * (1.0f / DM) - mu * mu;
  float rs  = rsqrtf(var + 1e-5f);
  short* o = out + (size_t)row * DM;
  #pragma unroll
  for (int i = 0; i < 12; i++){
    int c = lane + i * 64;
    o[c] = f2bf((v[i] - mu) * rs * sc[c] + bi[c]);
  }
}

// ---- split-K reduce + residual + bias + NEXT-layer LN, wave per row --------
__global__ __launch_bounds__(256) void redln_k(float* __restrict__ h,
    const float* __restrict__ p0, const float* __restrict__ p1,
    const float* __restrict__ bias,
    const float* __restrict__ sc, const float* __restrict__ bi,
    short* __restrict__ out)
{
  int w = threadIdx.x >> 6, lane = threadIdx.x & 63;
  int row = blockIdx.x * 4 + w;
  size_t off = (size_t)row * DM;
  float v[12];
  float s = 0.f, s2 = 0.f;
  #pragma unroll
  for (int i = 0; i < 12; i++){
    int c = lane + i * 64;
    float xv = h[off + c] + p0[off + c] + p1[off + c] + bias[c];
    h[off + c] = xv;
    v[i] = xv; s += xv; s2 += xv * xv;
  }
  #pragma unroll
  for (int o = 32; o; o >>= 1){ s += __shfl_xor(s, o); s2 += __shfl_xor(s2, o); }
  float mu  = s * (1.0f / DM);
  float var = s2 * (1.0f / DM) - mu * mu;
  float rs  = rsqrtf(var + 1e-5f);
  #pragma unroll
  for (int i = 0; i < 12; i++){
    int c = lane + i * 64;
    out[off + c] = f2bf((v[i] - mu) * rs * sc[c] + bi[c]);
  }
}

// ---------------- transpose-cast: W [K][N] f32 -> WT [Nt*64][K] bf16 --------
__global__ __launch_bounds__(256) void tc_k(const float* __restrict__ in,
    short* __restrict__ out, int K, int N, int ntiles, int per_mat,
    size_t in_stride, size_t out_stride)
{
  __shared__ short sh[64][65];
  int b = blockIdx.x;
  int l = b / per_mat, r = b - l * per_mat;
  int nt = r % ntiles, kt = r / ntiles;
  const float* ip = in + (size_t)l * in_stride;
  short* op = out + (size_t)l * out_stride;
  int n0 = nt * 64, k0 = kt * 64;
  int tid = threadIdx.x;
  if ((N & 3) == 0){
    #pragma unroll
    for (int it = 0; it < 4; it++){
      int idx = it * 256 + tid;
      int k = idx >> 4, n4 = (idx & 15) * 4;
      float4 v = *(const float4*)(ip + (size_t)(k0 + k) * N + n0 + n4);
      sh[k][n4+0] = f2bf(v.x); sh[k][n4+1] = f2bf(v.y);
      sh[k][n4+2] = f2bf(v.z); sh[k][n4+3] = f2bf(v.w);
    }
  } else {
    #pragma unroll
    for (int it = 0; it < 16; it++){
      int idx = it * 256 + tid;
      int k = idx >> 6, n = idx & 63;
      float v = (n0 + n < N) ? ip[(size_t)(k0 + k) * N + n0 + n] : 0.f;
      sh[k][n] = f2bf(v);
    }
  }
  __syncthreads();
  #pragma unroll
  for (int it = 0; it < 2; it++){
    int n = it * 32 + (tid >> 3);
    int kc = (tid & 7) * 8;
    bf16x8 v;
    #pragma unroll
    for (int u = 0; u < 8; u++) v[u] = sh[kc + u][n];
    *(bf16x8*)(op + (size_t)(n0 + n) * K + k0 + kc) = v;
  }
}

// ---------------- QKV transpose-cast: [L][H][768][64] x3 -> [L][2304][768] --
__global__ __launch_bounds__(256) void tcqkv_k(const float* __restrict__ Wq,
    const float* __restrict__ Wk, const float* __restrict__ Wv,
    short* __restrict__ out)
{
  __shared__ short sh[64][65];
  int b = blockIdx.x;            // L*H*12
  int l = b / 144; int r = b - l * 144;
  int h = r / 12, kt = r - h * 12;
  int tid = threadIdx.x;
  for (int p = 0; p < 3; p++){
    const float* ip = (p == 0 ? Wq : p == 1 ? Wk : Wv)
                      + ((size_t)(l * NH + h) * DM + kt * 64) * 64;
    if (p) __syncthreads();
    #pragma unroll
    for (int it = 0; it < 4; it++){
      int idx = it * 256 + tid;
      int k = idx >> 4, e4 = (idx & 15) * 4;
      float4 v = *(const float4*)(ip + (size_t)k * 64 + e4);
      sh[k][e4+0] = f2bf(v.x); sh[k][e4+1] = f2bf(v.y);
      sh[k][e4+2] = f2bf(v.z); sh[k][e4+3] = f2bf(v.w);
    }
    __syncthreads();
    short* op = out + (size_t)l * 2304 * DM + (size_t)(p * DM + h * 64) * DM;
    #pragma unroll
    for (int it = 0; it < 2; it++){
      int e = it * 32 + (tid >> 3);
      int kc = (tid & 7) * 8;
      bf16x8 v;
      #pragma unroll
      for (int u = 0; u < 8; u++) v[u] = sh[kc + u][e];
      *(bf16x8*)(op + (size_t)e * DM + kt * 64 + kc) = v;
    }
  }
}

// ---------------- MFMA GEMM v11: depth-2 pipeline EVERYWHERE, param BK ------
// A,B^T via gl16+XOR swizzle, counted vmcnt (never 0 in steady state).
// Per-layer: BK=64, DEPTH=2 (r14-verified). LM (MODE 3): BK=32 (r16-verified
// swizzle) + DEPTH=2 -> 3x16KB = 48KB LDS, 3 blocks/CU, 2 tiles in flight
// across 24 K-steps. LM block-time audit (r16): ~4,500cy/step vs ~160cy MFMA
// + ~1,200cy L2/LDS -> latency-depth bound; depth is the only lever that has
// ever paid here (r7, r14).
// Swizzle: BK=64: gs = g ^ (row&7). BK=32: gs = g ^ ((row>>1)&3) (row
// contributes (row&1)*16 to bank index; jointly walks all 8 quads).
// MODE 0: QKV fused; MODE 1: MLP1 gelu; MODE 2: MLP2 split-K plain stores;
// MODE 3: LM XCD-pinned panels (plain stores; NT falsified r13).
template<int MODE, int FI, int FJ, int BK>
__global__ __launch_bounds__(256) void mg_k(
    const short* __restrict__ A, const short* __restrict__ Bt,
    const float* __restrict__ b0, const float* __restrict__ b1,
    const float* __restrict__ b2,
    void* __restrict__ C0, void* __restrict__ C1, void* __restrict__ C2)
{
  constexpr int LDA    = (MODE == 2) ? DF_ : DM;
  constexpr int BM     = FI * 32;
  constexpr int BN     = FJ * 32;
  constexpr int ABYTES = BM * BK * 2;
  constexpr int BBYTES = BN * BK * 2;
  constexpr int TBYTES = ABYTES + BBYTES;
  constexpr int DEPTH  = 2;
  constexpr int NBUF   = DEPTH + 1;
  constexpr int GR     = BK / 8;             // 16B granules per LDS row
  constexpr int NCHA   = ABYTES / 4096;      // gl16 chunks for A
  constexpr int NCHB   = BBYTES / 4096;
  constexpr int W      = NCHA + NCHB;        // VMEM instrs per stage per wave
  __shared__ __align__(16) char lds[NBUF * TBYTES];

  int tid = threadIdx.x;
  int wid = tid >> 6, lane = tid & 63;
  int l15 = lane & 15, l4 = lane >> 4;
  int wr = wid >> 1, wc = wid & 1;

  int m0, n0;
  if (MODE == 3){
    int xcd = blockIdx.x & 7, slot = blockIdx.x >> 3;
    int nb = xcd + 8 * (slot >> 3);
    if (nb >= NPAN) return;
    m0 = (slot & 7) * BM;
    n0 = nb * BN;
  } else {
    m0 = blockIdx.x * BM;
    n0 = blockIdx.y * BN;
  }
  int kbeg = (MODE == 2) ? blockIdx.z * (DF_ / 2) : 0;
  int nk   = ((MODE == 2) ? DF_ / 2 : LDA) / BK;

  f32x4 acc[FI][FJ] = {};
  int wbase = (tid & ~63) * 16;

  auto stage = [&](int k0, int b){
    char* ab = lds + b * TBYTES;
    char* bb = ab + ABYTES;
    #pragma unroll
    for (int ia = 0; ia < NCHA; ia++){
      int d = ia * 256 + tid;
      int row = d / GR, g = d & (GR - 1);
      int gs;
      if constexpr (BK == 64) gs = g ^ (row & 7);
      else                    gs = g ^ ((row >> 1) & 3);
      gl16(A + (size_t)(m0 + row) * LDA + k0 + gs * 8, ab + ia * 4096 + wbase);
    }
    #pragma unroll
    for (int ib = 0; ib < NCHB; ib++){
      int d = ib * 256 + tid;
      int row = d / GR, g = d & (GR - 1);
      int gs;
      if constexpr (BK == 64) gs = g ^ (row & 7);
      else                    gs = g ^ ((row >> 1) & 3);
      gl16(Bt + (size_t)(n0 + row) * LDA + k0 + gs * 8, bb + ib * 4096 + wbase);
    }
  };

  // prologue: fill DEPTH tiles
  #pragma unroll
  for (int d = 0; d < DEPTH; d++)
    if (d < nk) stage(kbeg + d * BK, d);

  int cb = 0;                          // compute buffer
  int sb = DEPTH % NBUF;               // next stage buffer
  for (int t = 0; t < nk; ++t){
    if (t + DEPTH < nk){
      stage(kbeg + (t + DEPTH) * BK, sb);
      sb = (sb + 1 == NBUF) ? 0 : sb + 1;
      if constexpr (DEPTH * W == 4)       asm volatile("s_waitcnt vmcnt(4)"  ::: "memory");
      else if constexpr (DEPTH * W == 8)  asm volatile("s_waitcnt vmcnt(8)"  ::: "memory");
      else                                asm volatile("s_waitcnt vmcnt(16)" ::: "memory");
    } else if (DEPTH == 2 && t + 1 < nk){
      if constexpr (W == 4) asm volatile("s_waitcnt vmcnt(4)" ::: "memory");
      else                  asm volatile("s_waitcnt vmcnt(8)" ::: "memory");
    } else {
      asm volatile("s_waitcnt vmcnt(0)" ::: "memory");
    }
    __builtin_amdgcn_s_barrier();
    __builtin_amdgcn_sched_barrier(0);

    char* ab = lds + cb * TBYTES;
    char* bb = ab + ABYTES;
    cb = (cb + 1 == NBUF) ? 0 : cb + 1;
    #pragma unroll
    for (int kk = 0; kk < BK / 32; kk++){
      bf16x8 af[FI], bfr[FJ];
      #pragma unroll
      for (int i = 0; i < FI; i++){
        int row = wr * (FI * 16) + i * 16 + l15;
        int swz;
        if constexpr (BK == 64) swz = (kk * 4 + l4) ^ (row & 7);
        else                    swz = l4 ^ ((row >> 1) & 3);
        af[i] = *(const bf16x8*)(ab + row * (BK * 2) + swz * 16);
      }
      #pragma unroll
      for (int j = 0; j < FJ; j++){
        int row = wc * (FJ * 16) + j * 16 + l15;
        int swz;
        if constexpr (BK == 64) swz = (kk * 4 + l4) ^ (row & 7);
        else                    swz = l4 ^ ((row >> 1) & 3);
        bfr[j] = *(const bf16x8*)(bb + row * (BK * 2) + swz * 16);
      }
      #pragma unroll
      for (int i = 0; i < FI; i++)
        #pragma unroll
        for (int j = 0; j < FJ; j++)
          acc[i][j] = __builtin_amdgcn_mfma_f32_16x16x32_bf16(af[i], bfr[j], acc[i][j], 0, 0, 0);
    }
    __builtin_amdgcn_sched_barrier(0);
    __builtin_amdgcn_s_barrier();
  }

  #pragma unroll
  for (int i = 0; i < FI; i++){
    int rowb = m0 + wr * (FI * 16) + i * 16 + l4 * 4;
    #pragma unroll
    for (int j = 0; j < FJ; j++){
      int col = n0 + wc * (FJ * 16) + j * 16 + l15;
      if (MODE == 0){
        int p = col / DM, within = col - p * DM;
        const float* bp = (p == 0) ? b0 : (p == 1) ? b1 : b2;
        float bb2 = bp[within];
        int hd = within >> 6, e = within & 63;
        if (p < 2){
          short* dst = (short*)((p == 0) ? C0 : C1);
          #pragma unroll
          for (int r = 0; r < 4; r++)
            dst[((size_t)hd * TLEN + rowb + r) * 64 + e] = f2bf(acc[i][j][r] + bb2);
        } else {
          short4 pk;
          pk.x = f2bf(acc[i][j][0] + bb2); pk.y = f2bf(acc[i][j][1] + bb2);
          pk.z = f2bf(acc[i][j][2] + bb2); pk.w = f2bf(acc[i][j][3] + bb2);
          *(short4*)((short*)C2 + ((size_t)hd * 64 + e) * TLEN + rowb) = pk;
        }
      } else if (MODE == 1){
        #pragma unroll
        for (int r = 0; r < 4; r++)
          ((short*)C0)[(size_t)(rowb + r) * DF_ + col] =
              f2bf(gelu_exact(acc[i][j][r] + b0[col]));
      } else if (MODE == 2){
        float* dst = (float*)((blockIdx.z == 0) ? C0 : C1);
        #pragma unroll
        for (int r = 0; r < 4; r++)
          dst[(size_t)(rowb + r) * DM + col] = acc[i][j][r];
      } else {
        if (col < VC){
          #pragma unroll
          for (int r = 0; r < 4; r++)
            ((float*)C0)[(size_t)(rowb + r) * VC + col] = acc[i][j][r];
        }
      }
    }
  }
}

// ---------------- MFMA flash attention (unchanged, passing) -----------------
__global__ __launch_bounds__(256) void attn_k(const short* __restrict__ q,
    const short* __restrict__ k, const short* __restrict__ vt,
    float* __restrict__ h)
{
  __shared__ short P_lds[4][16][72];
  int tid = threadIdx.x;
  int wid = tid >> 6, lane = tid & 63;
  int l15 = lane & 15, l4 = lane >> 4;
  int head = blockIdx.x >> 4, qt = blockIdx.x & 15;
  int qb = qt * 64 + wid * 16;

  const short* qh = q  + (size_t)head * TLEN * 64;
  const short* kh = k  + (size_t)head * TLEN * 64;
  const short* vh = vt + (size_t)head * 64 * TLEN;

  bf16x8 qf[2];
  qf[0] = *(const bf16x8*)(qh + (size_t)(qb + l15) * 64 + l4 * 8);
  qf[1] = *(const bf16x8*)(qh + (size_t)(qb + l15) * 64 + 32 + l4 * 8);

  f32x4 O[4] = {};
  float mrow[4] = {-3e38f, -3e38f, -3e38f, -3e38f};
  float lrow[4] = {0.f, 0.f, 0.f, 0.f};

  for (int kv0 = 0; kv0 <= qb + 15; kv0 += 64){
    f32x4 S[4] = {};
    #pragma unroll
    for (int kk = 0; kk < 2; kk++){
      #pragma unroll
      for (int j = 0; j < 4; j++){
        bf16x8 kf = *(const bf16x8*)(kh + (size_t)(kv0 + j*16 + l15) * 64
                                     + kk*32 + l4*8);
        S[j] = __builtin_amdgcn_mfma_f32_16x16x32_bf16(qf[kk], kf, S[j], 0, 0, 0);
      }
    }
    if (kv0 + 63 > qb){
      #pragma unroll
      for (int j = 0; j < 4; j++){
        int kvc = kv0 + j*16 + l15;
        #pragma unroll
        for (int r = 0; r < 4; r++)
          if (kvc > qb + l4*4 + r) S[j][r] = -3e38f;
      }
    }
    #pragma unroll
    for (int r = 0; r < 4; r++){
      float mx = fmaxf(fmaxf(S[0][r], S[1][r]), fmaxf(S[2][r], S[3][r]));
      #pragma unroll
      for (int off = 1; off < 16; off <<= 1) mx = fmaxf(mx, __shfl_xor(mx, off));
      float mn = fmaxf(mrow[r], mx);
      float corr = __expf(mrow[r] - mn);
      mrow[r] = mn;
      float sm = 0.f;
      #pragma unroll
      for (int j = 0; j < 4; j++){
        float p = __expf(S[j][r] - mn);
        S[j][r] = p; sm += p;
      }
      #pragma unroll
      for (int off = 1; off < 16; off <<= 1) sm += __shfl_xor(sm, off);
      lrow[r] = lrow[r] * corr + sm;
      #pragma unroll
      for (int j = 0; j < 4; j++) O[j][r] *= corr;
    }
    #pragma unroll
    for (int j = 0; j < 4; j++)
      #pragma unroll
      for (int r = 0; r < 4; r++)
        P_lds[wid][l4*4 + r][j*16 + l15] = f2bf(S[j][r]);
    #pragma unroll
    for (int kk = 0; kk < 2; kk++){
      bf16x8 pa = *(const bf16x8*)(&P_lds[wid][l15][kk*32 + l4*8]);
      #pragma unroll
      for (int jd = 0; jd < 4; jd++){
        bf16x8 vf = *(const bf16x8*)(vh + (size_t)(jd*16 + l15) * TLEN
                                     + kv0 + kk*32 + l4*8);
        O[jd] = __builtin_amdgcn_mfma_f32_16x16x32_bf16(pa, vf, O[jd], 0, 0, 0);
      }
    }
  }

  #pragma unroll
  for (int r = 0; r < 4; r++){
    float inv = 1.0f / lrow[r];
    int t = qb + l4*4 + r;
    #pragma unroll
    for (int jd = 0; jd < 4; jd++){
      int d = head * 64 + jd*16 + l15;
      h[(size_t)t * DM + d] += O[jd][r] * inv;
    }
  }
}

extern "C" void kernel_launch(void* const* d_in, const int* in_sizes, int n_in,
                              void* d_out, int out_size, void* d_ws, size_t ws_size,
                              hipStream_t stream)
{
  const int*   x    = (const int*)  d_in[0];
  const float* wte  = (const float*)d_in[1];
  const float* wpe  = (const float*)d_in[2];
  const float* Wq   = (const float*)d_in[3];
  const float* bq   = (const float*)d_in[4];
  const float* Wk   = (const float*)d_in[5];
  const float* bk   = (const float*)d_in[6];
  const float* Wv   = (const float*)d_in[7];
  const float* bv   = (const float*)d_in[8];
  const float* ln1s = (const float*)d_in[9];
  const float* ln1b = (const float*)d_in[10];
  const float* W1   = (const float*)d_in[11];
  const float* b1   = (const float*)d_in[12];
  const float* W2   = (const float*)d_in[13];
  const float* b2   = (const float*)d_in[14];
  const float* ln2s = (const float*)d_in[15];
  const float* ln2b = (const float*)d_in[16];
  const float* lnfs = (const float*)d_in[17];
  const float* lnfb = (const float*)d_in[18];
  const float* Wlm  = (const float*)d_in[19];
  float* out = (float*)d_out;

  const size_t SZ_QKVT = (size_t)NL * 2304 * DM * 2;
  const size_t SZ_W1T  = (size_t)NL * DF_ * DM * 2;
  const size_t SZ_W2T  = (size_t)NL * DM * DF_ * 2;
  const size_t SZ_WLMT = (size_t)VCP * DM * 2;
  const size_t SZ_H    = (size_t)TLEN * DM * 4;   // fp32 h / partial
  const size_t SZ_BF   = (size_t)TLEN * DM * 2;   // bf16 activation

  char* ws = (char*)d_ws;
  short* wqkvT = (short*)ws;  ws += SZ_QKVT;
  short* w1T   = (short*)ws;  ws += SZ_W1T;
  short* w2T   = (short*)ws;  ws += SZ_W2T;
  short* wlmT  = (short*)ws;  ws += SZ_WLMT;
  float* h     = (float*)ws;  ws += SZ_H;
  short* qb    = (short*)ws;  ws += SZ_BF;
  short* kb    = (short*)ws;  ws += SZ_BF;
  short* vtb   = (short*)ws;  ws += SZ_BF;
  short* xnb   = (short*)ws;  ws += SZ_BF;
  short* mhb   = (short*)ws;  ws += (size_t)TLEN * DF_ * 2;
  float* p1    = (float*)ws;  // fresh 3 MB
  float* p0    = (float*)qb;  // overlays qb+kb (dead during MLP2/redln)

  tcqkv_k<<<NL*NH*12, 256, 0, stream>>>(Wq, Wk, Wv, wqkvT);
  tc_k<<<NL*48*12, 256, 0, stream>>>(W1, w1T, DM, DF_, 48, 576,
                                     (size_t)DM*DF_, (size_t)DM*DF_);
  tc_k<<<NL*12*48, 256, 0, stream>>>(W2, w2T, DF_, DM, 12, 576,
                                     (size_t)DM*DF_, (size_t)DM*DF_);
  tc_k<<<786*12, 256, 0, stream>>>(Wlm, wlmT, DM, VC, 786, 786*12, 0, 0);

  embedln_k<<<TLEN/4, 256, 0, stream>>>(x, wte, wpe, ln1s, ln1b, h, xnb);

  for (int l = 0; l < NL; ++l){
    mg_k<0,2,2,64><<<dim3(16,36), 256, 0, stream>>>(xnb, wqkvT + (size_t)l*2304*DM,
        bq + l*DM, bk + l*DM, bv + l*DM, qb, kb, vtb);
    attn_k<<<NH*16, 256, 0, stream>>>(qb, kb, vtb, h);
    ln_k<<<TLEN/4, 256, 0, stream>>>(h, ln2s + l*DM, ln2b + l*DM, xnb);
    mg_k<1,2,2,64><<<dim3(16,48), 256, 0, stream>>>(xnb, w1T + (size_t)l*DF_*DM,
        b1 + l*DF_, nullptr, nullptr, mhb, nullptr, nullptr);
    mg_k<2,2,2,64><<<dim3(16,12,2), 256, 0, stream>>>(mhb, w2T + (size_t)l*DM*DF_,
        nullptr, nullptr, nullptr, p0, p1, nullptr);
    const float* nsc = (l < NL-1) ? ln1s + (l+1)*DM : lnfs;
    const float* nbi = (l < NL-1) ? ln1b + (l+1)*DM : lnfb;
    redln_k<<<TLEN/4, 256, 0, stream>>>(h, p0, p1, b2 + l*DM, nsc, nbi, xnb);
  }

  // LM head: 128x128 XCD-pinned, BK=32 DEPTH=2 -> 48KB LDS, 3 blocks/CU,
  // 2 tiles in flight over 24 K-steps
  mg_k<3,4,4,32><<<3200, 256, 0, stream>>>(xnb, wlmT,
      nullptr, nullptr, nullptr, out, nullptr, nullptr);
}

// Round 18
// 1221.900 us; speedup vs baseline: 1.0726x; 1.0637x over previous
//
#include <hip/hip_runtime.h>
#include <math.h>

#define TLEN 1024
#define DM   768
#define NH   12
#define HSZ  64
#define DF_  3072
#define NL   12
#define VC   50257
#define VCP  50304          // VC padded to 64
#define NPAN (VCP/128)      // 393 LM N-panels

typedef __attribute__((ext_vector_type(8))) short bf16x8;
typedef __attribute__((ext_vector_type(4))) float f32x4;

__device__ __forceinline__ float gelu_exact(float x){
  return 0.5f * x * (1.0f + erff(x * 0.70710678118654752f));
}
__device__ __forceinline__ short f2bf(float f){
  union { float f; unsigned u; } x; x.f = f;
  unsigned r = x.u + 0x7fffu + ((x.u >> 16) & 1u);
  return (short)(r >> 16);
}
__device__ __forceinline__ void gl16(const void* g, void* l){
  __builtin_amdgcn_global_load_lds(
      (const __attribute__((address_space(1))) unsigned int*)g,
      (__attribute__((address_space(3))) unsigned int*)l, 16, 0, 0);
}

// ---------------- embedding fused with layer-0 ln1: wave per row ------------
__global__ __launch_bounds__(256) void embedln_k(const int* __restrict__ x,
    const float* __restrict__ wte, const float* __restrict__ wpe,
    const float* __restrict__ sc, const float* __restrict__ bi,
    float* __restrict__ h, short* __restrict__ out)
{
  int w = threadIdx.x >> 6, lane = threadIdx.x & 63;
  int t = blockIdx.x * 4 + w;
  int tok = x[t];
  size_t off = (size_t)t * DM;
  float v[12];
  float s = 0.f, s2 = 0.f;
  #pragma unroll
  for (int i = 0; i < 12; i++){
    int c = lane + i * 64;
    float xv = wte[(size_t)tok * DM + c] + wpe[off + c];
    h[off + c] = xv;
    v[i] = xv; s += xv; s2 += xv * xv;
  }
  #pragma unroll
  for (int o = 32; o; o >>= 1){ s += __shfl_xor(s, o); s2 += __shfl_xor(s2, o); }
  float mu = s * (1.0f / DM);
  float var = s2 * (1.0f / DM) - mu * mu;
  float rs = rsqrtf(var + 1e-5f);
  #pragma unroll
  for (int i = 0; i < 12; i++){
    int c = lane + i * 64;
    out[off + c] = f2bf((v[i] - mu) * rs * sc[c] + bi[c]);
  }
}

// ---------------- layernorm: fp32 in, bf16 out (used for ln2) ---------------
__global__ __launch_bounds__(256) void ln_k(const float* __restrict__ in,
    const float* __restrict__ sc, const float* __restrict__ bi,
    short* __restrict__ out)
{
  int w = threadIdx.x >> 6, lane = threadIdx.x & 63;
  int row = blockIdx.x * 4 + w;
  const float* r = in + (size_t)row * DM;
  float v[12];
  float s = 0.f, s2 = 0.f;
  #pragma unroll
  for (int i = 0; i < 12; i++){
    float xv = r[lane + i * 64];
    v[i] = xv; s += xv; s2 += xv * xv;
  }
  #pragma unroll
  for (int o = 32; o; o >>= 1){ s += __shfl_xor(s, o); s2 += __shfl_xor(s2, o); }
  float mu  = s * (1.0f / DM);
  float var = s2 * (1.0f / DM) - mu * mu;
  float rs  = rsqrtf(var + 1e-5f);
  short* o = out + (size_t)row * DM;
  #pragma unroll
  for (int i = 0; i < 12; i++){
    int c = lane + i * 64;
    o[c] = f2bf((v[i] - mu) * rs * sc[c] + bi[c]);
  }
}

// ---- split-K reduce + residual + bias + NEXT-layer LN, wave per row --------
__global__ __launch_bounds__(256) void redln_k(float* __restrict__ h,
    const float* __restrict__ p0, const float* __restrict__ p1,
    const float* __restrict__ bias,
    const float* __restrict__ sc, const float* __restrict__ bi,
    short* __restrict__ out)
{
  int w = threadIdx.x >> 6, lane = threadIdx.x & 63;
  int row = blockIdx.x * 4 + w;
  size_t off = (size_t)row * DM;
  float v[12];
  float s = 0.f, s2 = 0.f;
  #pragma unroll
  for (int i = 0; i < 12; i++){
    int c = lane + i * 64;
    float xv = h[off + c] + p0[off + c] + p1[off + c] + bias[c];
    h[off + c] = xv;
    v[i] = xv; s += xv; s2 += xv * xv;
  }
  #pragma unroll
  for (int o = 32; o; o >>= 1){ s += __shfl_xor(s, o); s2 += __shfl_xor(s2, o); }
  float mu  = s * (1.0f / DM);
  float var = s2 * (1.0f / DM) - mu * mu;
  float rs  = rsqrtf(var + 1e-5f);
  #pragma unroll
  for (int i = 0; i < 12; i++){
    int c = lane + i * 64;
    out[off + c] = f2bf((v[i] - mu) * rs * sc[c] + bi[c]);
  }
}

// ---------------- transpose-cast: W [K][N] f32 -> WT [Nt*64][K] bf16 --------
__global__ __launch_bounds__(256) void tc_k(const float* __restrict__ in,
    short* __restrict__ out, int K, int N, int ntiles, int per_mat,
    size_t in_stride, size_t out_stride)
{
  __shared__ short sh[64][65];
  int b = blockIdx.x;
  int l = b / per_mat, r = b - l * per_mat;
  int nt = r % ntiles, kt = r / ntiles;
  const float* ip = in + (size_t)l * in_stride;
  short* op = out + (size_t)l * out_stride;
  int n0 = nt * 64, k0 = kt * 64;
  int tid = threadIdx.x;
  if ((N & 3) == 0){
    #pragma unroll
    for (int it = 0; it < 4; it++){
      int idx = it * 256 + tid;
      int k = idx >> 4, n4 = (idx & 15) * 4;
      float4 v = *(const float4*)(ip + (size_t)(k0 + k) * N + n0 + n4);
      sh[k][n4+0] = f2bf(v.x); sh[k][n4+1] = f2bf(v.y);
      sh[k][n4+2] = f2bf(v.z); sh[k][n4+3] = f2bf(v.w);
    }
  } else {
    #pragma unroll
    for (int it = 0; it < 16; it++){
      int idx = it * 256 + tid;
      int k = idx >> 6, n = idx & 63;
      float v = (n0 + n < N) ? ip[(size_t)(k0 + k) * N + n0 + n] : 0.f;
      sh[k][n] = f2bf(v);
    }
  }
  __syncthreads();
  #pragma unroll
  for (int it = 0; it < 2; it++){
    int n = it * 32 + (tid >> 3);
    int kc = (tid & 7) * 8;
    bf16x8 v;
    #pragma unroll
    for (int u = 0; u < 8; u++) v[u] = sh[kc + u][n];
    *(bf16x8*)(op + (size_t)(n0 + n) * K + k0 + kc) = v;
  }
}

// ---------------- QKV transpose-cast: [L][H][768][64] x3 -> [L][2304][768] --
__global__ __launch_bounds__(256) void tcqkv_k(const float* __restrict__ Wq,
    const float* __restrict__ Wk, const float* __restrict__ Wv,
    short* __restrict__ out)
{
  __shared__ short sh[64][65];
  int b = blockIdx.x;            // L*H*12
  int l = b / 144; int r = b - l * 144;
  int h = r / 12, kt = r - h * 12;
  int tid = threadIdx.x;
  for (int p = 0; p < 3; p++){
    const float* ip = (p == 0 ? Wq : p == 1 ? Wk : Wv)
                      + ((size_t)(l * NH + h) * DM + kt * 64) * 64;
    if (p) __syncthreads();
    #pragma unroll
    for (int it = 0; it < 4; it++){
      int idx = it * 256 + tid;
      int k = idx >> 4, e4 = (idx & 15) * 4;
      float4 v = *(const float4*)(ip + (size_t)k * 64 + e4);
      sh[k][e4+0] = f2bf(v.x); sh[k][e4+1] = f2bf(v.y);
      sh[k][e4+2] = f2bf(v.z); sh[k][e4+3] = f2bf(v.w);
    }
    __syncthreads();
    short* op = out + (size_t)l * 2304 * DM + (size_t)(p * DM + h * 64) * DM;
    #pragma unroll
    for (int it = 0; it < 2; it++){
      int e = it * 32 + (tid >> 3);
      int kc = (tid & 7) * 8;
      bf16x8 v;
      #pragma unroll
      for (int u = 0; u < 8; u++) v[u] = sh[kc + u][e];
      *(bf16x8*)(op + (size_t)e * DM + kt * 64 + kc) = v;
    }
  }
}

// ---------------- MFMA GEMM v11 (r17-verified, frozen) ----------------------
template<int MODE, int FI, int FJ, int BK>
__global__ __launch_bounds__(256) void mg_k(
    const short* __restrict__ A, const short* __restrict__ Bt,
    const float* __restrict__ b0, const float* __restrict__ b1,
    const float* __restrict__ b2,
    void* __restrict__ C0, void* __restrict__ C1, void* __restrict__ C2)
{
  constexpr int LDA    = (MODE == 2) ? DF_ : DM;
  constexpr int BM     = FI * 32;
  constexpr int BN     = FJ * 32;
  constexpr int ABYTES = BM * BK * 2;
  constexpr int BBYTES = BN * BK * 2;
  constexpr int TBYTES = ABYTES + BBYTES;
  constexpr int DEPTH  = 2;
  constexpr int NBUF   = DEPTH + 1;
  constexpr int GR     = BK / 8;
  constexpr int NCHA   = ABYTES / 4096;
  constexpr int NCHB   = BBYTES / 4096;
  constexpr int W      = NCHA + NCHB;
  __shared__ __align__(16) char lds[NBUF * TBYTES];

  int tid = threadIdx.x;
  int wid = tid >> 6, lane = tid & 63;
  int l15 = lane & 15, l4 = lane >> 4;
  int wr = wid >> 1, wc = wid & 1;

  int m0, n0;
  if (MODE == 3){
    int xcd = blockIdx.x & 7, slot = blockIdx.x >> 3;
    int nb = xcd + 8 * (slot >> 3);
    if (nb >= NPAN) return;
    m0 = (slot & 7) * BM;
    n0 = nb * BN;
  } else {
    m0 = blockIdx.x * BM;
    n0 = blockIdx.y * BN;
  }
  int kbeg = (MODE == 2) ? blockIdx.z * (DF_ / 2) : 0;
  int nk   = ((MODE == 2) ? DF_ / 2 : LDA) / BK;

  f32x4 acc[FI][FJ] = {};
  int wbase = (tid & ~63) * 16;

  auto stage = [&](int k0, int b){
    char* ab = lds + b * TBYTES;
    char* bb = ab + ABYTES;
    #pragma unroll
    for (int ia = 0; ia < NCHA; ia++){
      int d = ia * 256 + tid;
      int row = d / GR, g = d & (GR - 1);
      int gs;
      if constexpr (BK == 64) gs = g ^ (row & 7);
      else                    gs = g ^ ((row >> 1) & 3);
      gl16(A + (size_t)(m0 + row) * LDA + k0 + gs * 8, ab + ia * 4096 + wbase);
    }
    #pragma unroll
    for (int ib = 0; ib < NCHB; ib++){
      int d = ib * 256 + tid;
      int row = d / GR, g = d & (GR - 1);
      int gs;
      if constexpr (BK == 64) gs = g ^ (row & 7);
      else                    gs = g ^ ((row >> 1) & 3);
      gl16(Bt + (size_t)(n0 + row) * LDA + k0 + gs * 8, bb + ib * 4096 + wbase);
    }
  };

  #pragma unroll
  for (int d = 0; d < DEPTH; d++)
    if (d < nk) stage(kbeg + d * BK, d);

  int cb = 0;
  int sb = DEPTH % NBUF;
  for (int t = 0; t < nk; ++t){
    if (t + DEPTH < nk){
      stage(kbeg + (t + DEPTH) * BK, sb);
      sb = (sb + 1 == NBUF) ? 0 : sb + 1;
      if constexpr (DEPTH * W == 4)       asm volatile("s_waitcnt vmcnt(4)"  ::: "memory");
      else if constexpr (DEPTH * W == 8)  asm volatile("s_waitcnt vmcnt(8)"  ::: "memory");
      else                                asm volatile("s_waitcnt vmcnt(16)" ::: "memory");
    } else if (DEPTH == 2 && t + 1 < nk){
      if constexpr (W == 4) asm volatile("s_waitcnt vmcnt(4)" ::: "memory");
      else                  asm volatile("s_waitcnt vmcnt(8)" ::: "memory");
    } else {
      asm volatile("s_waitcnt vmcnt(0)" ::: "memory");
    }
    __builtin_amdgcn_s_barrier();
    __builtin_amdgcn_sched_barrier(0);

    char* ab = lds + cb * TBYTES;
    char* bb = ab + ABYTES;
    cb = (cb + 1 == NBUF) ? 0 : cb + 1;
    #pragma unroll
    for (int kk = 0; kk < BK / 32; kk++){
      bf16x8 af[FI], bfr[FJ];
      #pragma unroll
      for (int i = 0; i < FI; i++){
        int row = wr * (FI * 16) + i * 16 + l15;
        int swz;
        if constexpr (BK == 64) swz = (kk * 4 + l4) ^ (row & 7);
        else                    swz = l4 ^ ((row >> 1) & 3);
        af[i] = *(const bf16x8*)(ab + row * (BK * 2) + swz * 16);
      }
      #pragma unroll
      for (int j = 0; j < FJ; j++){
        int row = wc * (FJ * 16) + j * 16 + l15;
        int swz;
        if constexpr (BK == 64) swz = (kk * 4 + l4) ^ (row & 7);
        else                    swz = l4 ^ ((row >> 1) & 3);
        bfr[j] = *(const bf16x8*)(bb + row * (BK * 2) + swz * 16);
      }
      #pragma unroll
      for (int i = 0; i < FI; i++)
        #pragma unroll
        for (int j = 0; j < FJ; j++)
          acc[i][j] = __builtin_amdgcn_mfma_f32_16x16x32_bf16(af[i], bfr[j], acc[i][j], 0, 0, 0);
    }
    __builtin_amdgcn_sched_barrier(0);
    __builtin_amdgcn_s_barrier();
  }

  #pragma unroll
  for (int i = 0; i < FI; i++){
    int rowb = m0 + wr * (FI * 16) + i * 16 + l4 * 4;
    #pragma unroll
    for (int j = 0; j < FJ; j++){
      int col = n0 + wc * (FJ * 16) + j * 16 + l15;
      if (MODE == 0){
        int p = col / DM, within = col - p * DM;
        const float* bp = (p == 0) ? b0 : (p == 1) ? b1 : b2;
        float bb2 = bp[within];
        int hd = within >> 6, e = within & 63;
        if (p < 2){
          short* dst = (short*)((p == 0) ? C0 : C1);
          #pragma unroll
          for (int r = 0; r < 4; r++)
            dst[((size_t)hd * TLEN + rowb + r) * 64 + e] = f2bf(acc[i][j][r] + bb2);
        } else {
          short4 pk;
          pk.x = f2bf(acc[i][j][0] + bb2); pk.y = f2bf(acc[i][j][1] + bb2);
          pk.z = f2bf(acc[i][j][2] + bb2); pk.w = f2bf(acc[i][j][3] + bb2);
          *(short4*)((short*)C2 + ((size_t)hd * 64 + e) * TLEN + rowb) = pk;
        }
      } else if (MODE == 1){
        #pragma unroll
        for (int r = 0; r < 4; r++)
          ((short*)C0)[(size_t)(rowb + r) * DF_ + col] =
              f2bf(gelu_exact(acc[i][j][r] + b0[col]));
      } else if (MODE == 2){
        float* dst = (float*)((blockIdx.z == 0) ? C0 : C1);
        #pragma unroll
        for (int r = 0; r < 4; r++)
          dst[(size_t)(rowb + r) * DM + col] = acc[i][j][r];
      } else {
        if (col < VC){
          #pragma unroll
          for (int r = 0; r < 4; r++)
            ((float*)C0)[(size_t)(rowb + r) * VC + col] = acc[i][j][r];
        }
      }
    }
  }
}

// ---------------- MFMA flash attention v2: kv-SPLIT across waves ------------
// Grid NH*64 = 768 blocks (3/CU). Block owns 16 q-rows (tile = blockIdx&63).
// 4 waves split the kv range into <=ceil(nsteps/4)-step chunks, each running
// the r4-verified per-chunk online-softmax pipeline (only loop bounds differ;
// causal mask still fires only on the final straddling step). Partials merged
// via LDS (stride-25 padded = conflict-free): O = sum O_w e^(m_w-M),
// L = sum l_w e^(m_w-M); empty waves contribute e^(-3e38-M) = 0.
__global__ __launch_bounds__(256) void attn_k(const short* __restrict__ q,
    const short* __restrict__ k, const short* __restrict__ vt,
    float* __restrict__ h)
{
  __shared__ short P_lds[4][16][72];
  __shared__ float M_lds[4][64][25];   // [wave][lane][0..3 m,4..7 l,8..23 O]
  int tid = threadIdx.x;
  int wid = tid >> 6, lane = tid & 63;
  int l15 = lane & 15, l4 = lane >> 4;
  int head = blockIdx.x >> 6, tile = blockIdx.x & 63;
  int qb = tile * 16;

  const short* qh = q  + (size_t)head * TLEN * 64;
  const short* kh = k  + (size_t)head * TLEN * 64;
  const short* vh = vt + (size_t)head * 64 * TLEN;

  bf16x8 qf[2];
  qf[0] = *(const bf16x8*)(qh + (size_t)(qb + l15) * 64 + l4 * 8);
  qf[1] = *(const bf16x8*)(qh + (size_t)(qb + l15) * 64 + 32 + l4 * 8);

  int nsteps = (qb + 15) / 64 + 1;          // 64-kv steps for these rows
  int spw = (nsteps + 3) >> 2;
  int s_beg = wid * spw;
  int s_end = s_beg + spw; if (s_end > nsteps) s_end = nsteps;

  f32x4 O[4] = {};
  float mrow[4] = {-3e38f, -3e38f, -3e38f, -3e38f};
  float lrow[4] = {0.f, 0.f, 0.f, 0.f};

  for (int s = s_beg; s < s_end; ++s){
    int kv0 = s * 64;
    f32x4 S[4] = {};
    #pragma unroll
    for (int kk = 0; kk < 2; kk++){
      #pragma unroll
      for (int j = 0; j < 4; j++){
        bf16x8 kf = *(const bf16x8*)(kh + (size_t)(kv0 + j*16 + l15) * 64
                                     + kk*32 + l4*8);
        S[j] = __builtin_amdgcn_mfma_f32_16x16x32_bf16(qf[kk], kf, S[j], 0, 0, 0);
      }
    }
    if (kv0 + 63 > qb){                      // only the diagonal step masks
      #pragma unroll
      for (int j = 0; j < 4; j++){
        int kvc = kv0 + j*16 + l15;
        #pragma unroll
        for (int r = 0; r < 4; r++)
          if (kvc > qb + l4*4 + r) S[j][r] = -3e38f;
      }
    }
    #pragma unroll
    for (int r = 0; r < 4; r++){
      float mx = fmaxf(fmaxf(S[0][r], S[1][r]), fmaxf(S[2][r], S[3][r]));
      #pragma unroll
      for (int off = 1; off < 16; off <<= 1) mx = fmaxf(mx, __shfl_xor(mx, off));
      float mn = fmaxf(mrow[r], mx);
      float corr = __expf(mrow[r] - mn);
      mrow[r] = mn;
      float sm = 0.f;
      #pragma unroll
      for (int j = 0; j < 4; j++){
        float p = __expf(S[j][r] - mn);
        S[j][r] = p; sm += p;
      }
      #pragma unroll
      for (int off = 1; off < 16; off <<= 1) sm += __shfl_xor(sm, off);
      lrow[r] = lrow[r] * corr + sm;
      #pragma unroll
      for (int j = 0; j < 4; j++) O[j][r] *= corr;
    }
    #pragma unroll
    for (int j = 0; j < 4; j++)
      #pragma unroll
      for (int r = 0; r < 4; r++)
        P_lds[wid][l4*4 + r][j*16 + l15] = f2bf(S[j][r]);
    #pragma unroll
    for (int kk = 0; kk < 2; kk++){
      bf16x8 pa = *(const bf16x8*)(&P_lds[wid][l15][kk*32 + l4*8]);
      #pragma unroll
      for (int jd = 0; jd < 4; jd++){
        bf16x8 vf = *(const bf16x8*)(vh + (size_t)(jd*16 + l15) * TLEN
                                     + kv0 + kk*32 + l4*8);
        O[jd] = __builtin_amdgcn_mfma_f32_16x16x32_bf16(pa, vf, O[jd], 0, 0, 0);
      }
    }
  }

  // ---- publish partials ----
  #pragma unroll
  for (int r = 0; r < 4; r++){
    M_lds[wid][lane][r]     = mrow[r];
    M_lds[wid][lane][4 + r] = lrow[r];
  }
  #pragma unroll
  for (int jd = 0; jd < 4; jd++)
    #pragma unroll
    for (int r = 0; r < 4; r++)
      M_lds[wid][lane][8 + jd*4 + r] = O[jd][r];
  __syncthreads();

  // ---- wave 0 merges and writes ----
  if (wid == 0){
    float Mt[4], Lt[4];
    f32x4 Ot[4] = {};
    #pragma unroll
    for (int r = 0; r < 4; r++){
      Mt[r] = fmaxf(fmaxf(M_lds[0][lane][r], M_lds[1][lane][r]),
                    fmaxf(M_lds[2][lane][r], M_lds[3][lane][r]));
      Lt[r] = 0.f;
    }
    #pragma unroll
    for (int w = 0; w < 4; w++){
      #pragma unroll
      for (int r = 0; r < 4; r++){
        float c = __expf(M_lds[w][lane][r] - Mt[r]);
        Lt[r] += M_lds[w][lane][4 + r] * c;
        #pragma unroll
        for (int jd = 0; jd < 4; jd++)
          Ot[jd][r] += M_lds[w][lane][8 + jd*4 + r] * c;
      }
    }
    #pragma unroll
    for (int r = 0; r < 4; r++){
      float inv = 1.0f / Lt[r];
      int t = qb + l4*4 + r;
      #pragma unroll
      for (int jd = 0; jd < 4; jd++){
        int d = head * 64 + jd*16 + l15;
        h[(size_t)t * DM + d] += Ot[jd][r] * inv;
      }
    }
  }
}

extern "C" void kernel_launch(void* const* d_in, const int* in_sizes, int n_in,
                              void* d_out, int out_size, void* d_ws, size_t ws_size,
                              hipStream_t stream)
{
  const int*   x    = (const int*)  d_in[0];
  const float* wte  = (const float*)d_in[1];
  const float* wpe  = (const float*)d_in[2];
  const float* Wq   = (const float*)d_in[3];
  const float* bq   = (const float*)d_in[4];
  const float* Wk   = (const float*)d_in[5];
  const float* bk   = (const float*)d_in[6];
  const float* Wv   = (const float*)d_in[7];
  const float* bv   = (const float*)d_in[8];
  const float* ln1s = (const float*)d_in[9];
  const float* ln1b = (const float*)d_in[10];
  const float* W1   = (const float*)d_in[11];
  const float* b1   = (const float*)d_in[12];
  const float* W2   = (const float*)d_in[13];
  const float* b2   = (const float*)d_in[14];
  const float* ln2s = (const float*)d_in[15];
  const float* ln2b = (const float*)d_in[16];
  const float* lnfs = (const float*)d_in[17];
  const float* lnfb = (const float*)d_in[18];
  const float* Wlm  = (const float*)d_in[19];
  float* out = (float*)d_out;

  const size_t SZ_QKVT = (size_t)NL * 2304 * DM * 2;
  const size_t SZ_W1T  = (size_t)NL * DF_ * DM * 2;
  const size_t SZ_W2T  = (size_t)NL * DM * DF_ * 2;
  const size_t SZ_WLMT = (size_t)VCP * DM * 2;
  const size_t SZ_H    = (size_t)TLEN * DM * 4;   // fp32 h / partial
  const size_t SZ_BF   = (size_t)TLEN * DM * 2;   // bf16 activation

  char* ws = (char*)d_ws;
  short* wqkvT = (short*)ws;  ws += SZ_QKVT;
  short* w1T   = (short*)ws;  ws += SZ_W1T;
  short* w2T   = (short*)ws;  ws += SZ_W2T;
  short* wlmT  = (short*)ws;  ws += SZ_WLMT;
  float* h     = (float*)ws;  ws += SZ_H;
  short* qb    = (short*)ws;  ws += SZ_BF;
  short* kb    = (short*)ws;  ws += SZ_BF;
  short* vtb   = (short*)ws;  ws += SZ_BF;
  short* xnb   = (short*)ws;  ws += SZ_BF;
  short* mhb   = (short*)ws;  ws += (size_t)TLEN * DF_ * 2;
  float* p1    = (float*)ws;  // fresh 3 MB
  float* p0    = (float*)qb;  // overlays qb+kb (dead during MLP2/redln)

  tcqkv_k<<<NL*NH*12, 256, 0, stream>>>(Wq, Wk, Wv, wqkvT);
  tc_k<<<NL*48*12, 256, 0, stream>>>(W1, w1T, DM, DF_, 48, 576,
                                     (size_t)DM*DF_, (size_t)DM*DF_);
  tc_k<<<NL*12*48, 256, 0, stream>>>(W2, w2T, DF_, DM, 12, 576,
                                     (size_t)DM*DF_, (size_t)DM*DF_);
  tc_k<<<786*12, 256, 0, stream>>>(Wlm, wlmT, DM, VC, 786, 786*12, 0, 0);

  embedln_k<<<TLEN/4, 256, 0, stream>>>(x, wte, wpe, ln1s, ln1b, h, xnb);

  for (int l = 0; l < NL; ++l){
    mg_k<0,2,2,64><<<dim3(16,36), 256, 0, stream>>>(xnb, wqkvT + (size_t)l*2304*DM,
        bq + l*DM, bk + l*DM, bv + l*DM, qb, kb, vtb);
    attn_k<<<NH*64, 256, 0, stream>>>(qb, kb, vtb, h);
    ln_k<<<TLEN/4, 256, 0, stream>>>(h, ln2s + l*DM, ln2b + l*DM, xnb);
    mg_k<1,2,2,64><<<dim3(16,48), 256, 0, stream>>>(xnb, w1T + (size_t)l*DF_*DM,
        b1 + l*DF_, nullptr, nullptr, mhb, nullptr, nullptr);
    mg_k<2,2,2,64><<<dim3(16,12,2), 256, 0, stream>>>(mhb, w2T + (size_t)l*DM*DF_,
        nullptr, nullptr, nullptr, p0, p1, nullptr);
    const float* nsc = (l < NL-1) ? ln1s + (l+1)*DM : lnfs;
    const float* nbi = (l < NL-1) ? ln1b + (l+1)*DM : lnfb;
    redln_k<<<TLEN/4, 256, 0, stream>>>(h, p0, p1, b2 + l*DM, nsc, nbi, xnb);
  }

  // LM head: 128x128 XCD-pinned, BK=32 DEPTH=2 (r17 config)
  mg_k<3,4,4,32><<<3200, 256, 0, stream>>>(xnb, wlmT,
      nullptr, nullptr, nullptr, out, nullptr, nullptr);
}

// Round 19
// 1204.307 us; speedup vs baseline: 1.0883x; 1.0146x over previous
//
#include <hip/hip_runtime.h>
#include <math.h>

#define TLEN 1024
#define DM   768
#define NH   12
#define HSZ  64
#define DF_  3072
#define NL   12
#define VC   50257
#define VCP  50304          // VC padded to 64
#define NPAN (VCP/128)      // 393 LM N-panels

typedef __attribute__((ext_vector_type(8))) short bf16x8;
typedef __attribute__((ext_vector_type(4))) float f32x4;

__device__ __forceinline__ float gelu_exact(float x){
  return 0.5f * x * (1.0f + erff(x * 0.70710678118654752f));
}
__device__ __forceinline__ short f2bf(float f){
  union { float f; unsigned u; } x; x.f = f;
  unsigned r = x.u + 0x7fffu + ((x.u >> 16) & 1u);
  return (short)(r >> 16);
}
__device__ __forceinline__ void gl16(const void* g, void* l){
  __builtin_amdgcn_global_load_lds(
      (const __attribute__((address_space(1))) unsigned int*)g,
      (__attribute__((address_space(3))) unsigned int*)l, 16, 0, 0);
}

// ---------------- embedding fused with layer-0 ln1: wave per row ------------
__global__ __launch_bounds__(256) void embedln_k(const int* __restrict__ x,
    const float* __restrict__ wte, const float* __restrict__ wpe,
    const float* __restrict__ sc, const float* __restrict__ bi,
    float* __restrict__ h, short* __restrict__ out)
{
  int w = threadIdx.x >> 6, lane = threadIdx.x & 63;
  int t = blockIdx.x * 4 + w;
  int tok = x[t];
  size_t off = (size_t)t * DM;
  float v[12];
  float s = 0.f, s2 = 0.f;
  #pragma unroll
  for (int i = 0; i < 12; i++){
    int c = lane + i * 64;
    float xv = wte[(size_t)tok * DM + c] + wpe[off + c];
    h[off + c] = xv;
    v[i] = xv; s += xv; s2 += xv * xv;
  }
  #pragma unroll
  for (int o = 32; o; o >>= 1){ s += __shfl_xor(s, o); s2 += __shfl_xor(s2, o); }
  float mu = s * (1.0f / DM);
  float var = s2 * (1.0f / DM) - mu * mu;
  float rs = rsqrtf(var + 1e-5f);
  #pragma unroll
  for (int i = 0; i < 12; i++){
    int c = lane + i * 64;
    out[off + c] = f2bf((v[i] - mu) * rs * sc[c] + bi[c]);
  }
}

// ---------------- layernorm: fp32 in, bf16 out (used for ln2) ---------------
__global__ __launch_bounds__(256) void ln_k(const float* __restrict__ in,
    const float* __restrict__ sc, const float* __restrict__ bi,
    short* __restrict__ out)
{
  int w = threadIdx.x >> 6, lane = threadIdx.x & 63;
  int row = blockIdx.x * 4 + w;
  const float* r = in + (size_t)row * DM;
  float v[12];
  float s = 0.f, s2 = 0.f;
  #pragma unroll
  for (int i = 0; i < 12; i++){
    float xv = r[lane + i * 64];
    v[i] = xv; s += xv; s2 += xv * xv;
  }
  #pragma unroll
  for (int o = 32; o; o >>= 1){ s += __shfl_xor(s, o); s2 += __shfl_xor(s2, o); }
  float mu  = s * (1.0f / DM);
  float var = s2 * (1.0f / DM) - mu * mu;
  float rs  = rsqrtf(var + 1e-5f);
  short* o = out + (size_t)row * DM;
  #pragma unroll
  for (int i = 0; i < 12; i++){
    int c = lane + i * 64;
    o[c] = f2bf((v[i] - mu) * rs * sc[c] + bi[c]);
  }
}

// ---- split-K(4) reduce + residual + bias + NEXT-layer LN, wave per row -----
__global__ __launch_bounds__(256) void redln_k(float* __restrict__ h,
    const float* __restrict__ p0, const float* __restrict__ p1,
    const float* __restrict__ p2, const float* __restrict__ p3,
    const float* __restrict__ bias,
    const float* __restrict__ sc, const float* __restrict__ bi,
    short* __restrict__ out)
{
  int w = threadIdx.x >> 6, lane = threadIdx.x & 63;
  int row = blockIdx.x * 4 + w;
  size_t off = (size_t)row * DM;
  float v[12];
  float s = 0.f, s2 = 0.f;
  #pragma unroll
  for (int i = 0; i < 12; i++){
    int c = lane + i * 64;
    float xv = h[off + c] + ((p0[off + c] + p1[off + c])
             + (p2[off + c] + p3[off + c])) + bias[c];
    h[off + c] = xv;
    v[i] = xv; s += xv; s2 += xv * xv;
  }
  #pragma unroll
  for (int o = 32; o; o >>= 1){ s += __shfl_xor(s, o); s2 += __shfl_xor(s2, o); }
  float mu  = s * (1.0f / DM);
  float var = s2 * (1.0f / DM) - mu * mu;
  float rs  = rsqrtf(var + 1e-5f);
  #pragma unroll
  for (int i = 0; i < 12; i++){
    int c = lane + i * 64;
    out[off + c] = f2bf((v[i] - mu) * rs * sc[c] + bi[c]);
  }
}

// ---------------- transpose-cast: W [K][N] f32 -> WT [Nt*64][K] bf16 --------
__global__ __launch_bounds__(256) void tc_k(const float* __restrict__ in,
    short* __restrict__ out, int K, int N, int ntiles, int per_mat,
    size_t in_stride, size_t out_stride)
{
  __shared__ short sh[64][65];
  int b = blockIdx.x;
  int l = b / per_mat, r = b - l * per_mat;
  int nt = r % ntiles, kt = r / ntiles;
  const float* ip = in + (size_t)l * in_stride;
  short* op = out + (size_t)l * out_stride;
  int n0 = nt * 64, k0 = kt * 64;
  int tid = threadIdx.x;
  if ((N & 3) == 0){
    #pragma unroll
    for (int it = 0; it < 4; it++){
      int idx = it * 256 + tid;
      int k = idx >> 4, n4 = (idx & 15) * 4;
      float4 v = *(const float4*)(ip + (size_t)(k0 + k) * N + n0 + n4);
      sh[k][n4+0] = f2bf(v.x); sh[k][n4+1] = f2bf(v.y);
      sh[k][n4+2] = f2bf(v.z); sh[k][n4+3] = f2bf(v.w);
    }
  } else {
    #pragma unroll
    for (int it = 0; it < 16; it++){
      int idx = it * 256 + tid;
      int k = idx >> 6, n = idx & 63;
      float v = (n0 + n < N) ? ip[(size_t)(k0 + k) * N + n0 + n] : 0.f;
      sh[k][n] = f2bf(v);
    }
  }
  __syncthreads();
  #pragma unroll
  for (int it = 0; it < 2; it++){
    int n = it * 32 + (tid >> 3);
    int kc = (tid & 7) * 8;
    bf16x8 v;
    #pragma unroll
    for (int u = 0; u < 8; u++) v[u] = sh[kc + u][n];
    *(bf16x8*)(op + (size_t)(n0 + n) * K + k0 + kc) = v;
  }
}

// ---------------- QKV transpose-cast: [L][H][768][64] x3 -> [L][2304][768] --
__global__ __launch_bounds__(256) void tcqkv_k(const float* __restrict__ Wq,
    const float* __restrict__ Wk, const float* __restrict__ Wv,
    short* __restrict__ out)
{
  __shared__ short sh[64][65];
  int b = blockIdx.x;            // L*H*12
  int l = b / 144; int r = b - l * 144;
  int h = r / 12, kt = r - h * 12;
  int tid = threadIdx.x;
  for (int p = 0; p < 3; p++){
    const float* ip = (p == 0 ? Wq : p == 1 ? Wk : Wv)
                      + ((size_t)(l * NH + h) * DM + kt * 64) * 64;
    if (p) __syncthreads();
    #pragma unroll
    for (int it = 0; it < 4; it++){
      int idx = it * 256 + tid;
      int k = idx >> 4, e4 = (idx & 15) * 4;
      float4 v = *(const float4*)(ip + (size_t)k * 64 + e4);
      sh[k][e4+0] = f2bf(v.x); sh[k][e4+1] = f2bf(v.y);
      sh[k][e4+2] = f2bf(v.z); sh[k][e4+3] = f2bf(v.w);
    }
    __syncthreads();
    short* op = out + (size_t)l * 2304 * DM + (size_t)(p * DM + h * 64) * DM;
    #pragma unroll
    for (int it = 0; it < 2; it++){
      int e = it * 32 + (tid >> 3);
      int kc = (tid & 7) * 8;
      bf16x8 v;
      #pragma unroll
      for (int u = 0; u < 8; u++) v[u] = sh[kc + u][e];
      *(bf16x8*)(op + (size_t)e * DM + kt * 64 + kc) = v;
    }
  }
}

// ---------------- MFMA GEMM v12 (r17 pipeline; MODE2 now z=4) ---------------
// MODE 2: MLP2 split-K z=4 (768 blocks = perfect 3/CU fill); partials
// p0,p1,p2 in C0..C2 and p3 passed via b0 (cast). Per-z K = 768, nk = 12.
template<int MODE, int FI, int FJ, int BK>
__global__ __launch_bounds__(256) void mg_k(
    const short* __restrict__ A, const short* __restrict__ Bt,
    const float* __restrict__ b0, const float* __restrict__ b1,
    const float* __restrict__ b2,
    void* __restrict__ C0, void* __restrict__ C1, void* __restrict__ C2)
{
  constexpr int LDA    = (MODE == 2) ? DF_ : DM;
  constexpr int BM     = FI * 32;
  constexpr int BN     = FJ * 32;
  constexpr int ABYTES = BM * BK * 2;
  constexpr int BBYTES = BN * BK * 2;
  constexpr int TBYTES = ABYTES + BBYTES;
  constexpr int DEPTH  = 2;
  constexpr int NBUF   = DEPTH + 1;
  constexpr int GR     = BK / 8;
  constexpr int NCHA   = ABYTES / 4096;
  constexpr int NCHB   = BBYTES / 4096;
  constexpr int W      = NCHA + NCHB;
  __shared__ __align__(16) char lds[NBUF * TBYTES];

  int tid = threadIdx.x;
  int wid = tid >> 6, lane = tid & 63;
  int l15 = lane & 15, l4 = lane >> 4;
  int wr = wid >> 1, wc = wid & 1;

  int m0, n0;
  if (MODE == 3){
    int xcd = blockIdx.x & 7, slot = blockIdx.x >> 3;
    int nb = xcd + 8 * (slot >> 3);
    if (nb >= NPAN) return;
    m0 = (slot & 7) * BM;
    n0 = nb * BN;
  } else {
    m0 = blockIdx.x * BM;
    n0 = blockIdx.y * BN;
  }
  int kbeg = (MODE == 2) ? blockIdx.z * (DF_ / 4) : 0;
  int nk   = ((MODE == 2) ? DF_ / 4 : LDA) / BK;

  f32x4 acc[FI][FJ] = {};
  int wbase = (tid & ~63) * 16;

  auto stage = [&](int k0, int b){
    char* ab = lds + b * TBYTES;
    char* bb = ab + ABYTES;
    #pragma unroll
    for (int ia = 0; ia < NCHA; ia++){
      int d = ia * 256 + tid;
      int row = d / GR, g = d & (GR - 1);
      int gs;
      if constexpr (BK == 64) gs = g ^ (row & 7);
      else                    gs = g ^ ((row >> 1) & 3);
      gl16(A + (size_t)(m0 + row) * LDA + k0 + gs * 8, ab + ia * 4096 + wbase);
    }
    #pragma unroll
    for (int ib = 0; ib < NCHB; ib++){
      int d = ib * 256 + tid;
      int row = d / GR, g = d & (GR - 1);
      int gs;
      if constexpr (BK == 64) gs = g ^ (row & 7);
      else                    gs = g ^ ((row >> 1) & 3);
      gl16(Bt + (size_t)(n0 + row) * LDA + k0 + gs * 8, bb + ib * 4096 + wbase);
    }
  };

  #pragma unroll
  for (int d = 0; d < DEPTH; d++)
    if (d < nk) stage(kbeg + d * BK, d);

  int cb = 0;
  int sb = DEPTH % NBUF;
  for (int t = 0; t < nk; ++t){
    if (t + DEPTH < nk){
      stage(kbeg + (t + DEPTH) * BK, sb);
      sb = (sb + 1 == NBUF) ? 0 : sb + 1;
      if constexpr (DEPTH * W == 4)       asm volatile("s_waitcnt vmcnt(4)"  ::: "memory");
      else if constexpr (DEPTH * W == 8)  asm volatile("s_waitcnt vmcnt(8)"  ::: "memory");
      else                                asm volatile("s_waitcnt vmcnt(16)" ::: "memory");
    } else if (DEPTH == 2 && t + 1 < nk){
      if constexpr (W == 4) asm volatile("s_waitcnt vmcnt(4)" ::: "memory");
      else                  asm volatile("s_waitcnt vmcnt(8)" ::: "memory");
    } else {
      asm volatile("s_waitcnt vmcnt(0)" ::: "memory");
    }
    __builtin_amdgcn_s_barrier();
    __builtin_amdgcn_sched_barrier(0);

    char* ab = lds + cb * TBYTES;
    char* bb = ab + ABYTES;
    cb = (cb + 1 == NBUF) ? 0 : cb + 1;
    #pragma unroll
    for (int kk = 0; kk < BK / 32; kk++){
      bf16x8 af[FI], bfr[FJ];
      #pragma unroll
      for (int i = 0; i < FI; i++){
        int row = wr * (FI * 16) + i * 16 + l15;
        int swz;
        if constexpr (BK == 64) swz = (kk * 4 + l4) ^ (row & 7);
        else                    swz = l4 ^ ((row >> 1) & 3);
        af[i] = *(const bf16x8*)(ab + row * (BK * 2) + swz * 16);
      }
      #pragma unroll
      for (int j = 0; j < FJ; j++){
        int row = wc * (FJ * 16) + j * 16 + l15;
        int swz;
        if constexpr (BK == 64) swz = (kk * 4 + l4) ^ (row & 7);
        else                    swz = l4 ^ ((row >> 1) & 3);
        bfr[j] = *(const bf16x8*)(bb + row * (BK * 2) + swz * 16);
      }
      #pragma unroll
      for (int i = 0; i < FI; i++)
        #pragma unroll
        for (int j = 0; j < FJ; j++)
          acc[i][j] = __builtin_amdgcn_mfma_f32_16x16x32_bf16(af[i], bfr[j], acc[i][j], 0, 0, 0);
    }
    __builtin_amdgcn_sched_barrier(0);
    __builtin_amdgcn_s_barrier();
  }

  #pragma unroll
  for (int i = 0; i < FI; i++){
    int rowb = m0 + wr * (FI * 16) + i * 16 + l4 * 4;
    #pragma unroll
    for (int j = 0; j < FJ; j++){
      int col = n0 + wc * (FJ * 16) + j * 16 + l15;
      if (MODE == 0){
        int p = col / DM, within = col - p * DM;
        const float* bp = (p == 0) ? b0 : (p == 1) ? b1 : b2;
        float bb2 = bp[within];
        int hd = within >> 6, e = within & 63;
        if (p < 2){
          short* dst = (short*)((p == 0) ? C0 : C1);
          #pragma unroll
          for (int r = 0; r < 4; r++)
            dst[((size_t)hd * TLEN + rowb + r) * 64 + e] = f2bf(acc[i][j][r] + bb2);
        } else {
          short4 pk;
          pk.x = f2bf(acc[i][j][0] + bb2); pk.y = f2bf(acc[i][j][1] + bb2);
          pk.z = f2bf(acc[i][j][2] + bb2); pk.w = f2bf(acc[i][j][3] + bb2);
          *(short4*)((short*)C2 + ((size_t)hd * 64 + e) * TLEN + rowb) = pk;
        }
      } else if (MODE == 1){
        #pragma unroll
        for (int r = 0; r < 4; r++)
          ((short*)C0)[(size_t)(rowb + r) * DF_ + col] =
              f2bf(gelu_exact(acc[i][j][r] + b0[col]));
      } else if (MODE == 2){
        int z = blockIdx.z;
        float* dst = (z == 0) ? (float*)C0 : (z == 1) ? (float*)C1
                   : (z == 2) ? (float*)C2 : (float*)b0;   // b0 carries p3
        #pragma unroll
        for (int r = 0; r < 4; r++)
          dst[(size_t)(rowb + r) * DM + col] = acc[i][j][r];
      } else {
        if (col < VC){
          #pragma unroll
          for (int r = 0; r < 4; r++)
            ((float*)C0)[(size_t)(rowb + r) * VC + col] = acc[i][j][r];
        }
      }
    }
  }
}

// ---------------- MFMA flash attention v2: kv-split across waves (r18) ------
__global__ __launch_bounds__(256) void attn_k(const short* __restrict__ q,
    const short* __restrict__ k, const short* __restrict__ vt,
    float* __restrict__ h)
{
  __shared__ short P_lds[4][16][72];
  __shared__ float M_lds[4][64][25];
  int tid = threadIdx.x;
  int wid = tid >> 6, lane = tid & 63;
  int l15 = lane & 15, l4 = lane >> 4;
  int head = blockIdx.x >> 6, tile = blockIdx.x & 63;
  int qb = tile * 16;

  const short* qh = q  + (size_t)head * TLEN * 64;
  const short* kh = k  + (size_t)head * TLEN * 64;
  const short* vh = vt + (size_t)head * 64 * TLEN;

  bf16x8 qf[2];
  qf[0] = *(const bf16x8*)(qh + (size_t)(qb + l15) * 64 + l4 * 8);
  qf[1] = *(const bf16x8*)(qh + (size_t)(qb + l15) * 64 + 32 + l4 * 8);

  int nsteps = (qb + 15) / 64 + 1;
  int spw = (nsteps + 3) >> 2;
  int s_beg = wid * spw;
  int s_end = s_beg + spw; if (s_end > nsteps) s_end = nsteps;

  f32x4 O[4] = {};
  float mrow[4] = {-3e38f, -3e38f, -3e38f, -3e38f};
  float lrow[4] = {0.f, 0.f, 0.f, 0.f};

  for (int s = s_beg; s < s_end; ++s){
    int kv0 = s * 64;
    f32x4 S[4] = {};
    #pragma unroll
    for (int kk = 0; kk < 2; kk++){
      #pragma unroll
      for (int j = 0; j < 4; j++){
        bf16x8 kf = *(const bf16x8*)(kh + (size_t)(kv0 + j*16 + l15) * 64
                                     + kk*32 + l4*8);
        S[j] = __builtin_amdgcn_mfma_f32_16x16x32_bf16(qf[kk], kf, S[j], 0, 0, 0);
      }
    }
    if (kv0 + 63 > qb){
      #pragma unroll
      for (int j = 0; j < 4; j++){
        int kvc = kv0 + j*16 + l15;
        #pragma unroll
        for (int r = 0; r < 4; r++)
          if (kvc > qb + l4*4 + r) S[j][r] = -3e38f;
      }
    }
    #pragma unroll
    for (int r = 0; r < 4; r++){
      float mx = fmaxf(fmaxf(S[0][r], S[1][r]), fmaxf(S[2][r], S[3][r]));
      #pragma unroll
      for (int off = 1; off < 16; off <<= 1) mx = fmaxf(mx, __shfl_xor(mx, off));
      float mn = fmaxf(mrow[r], mx);
      float corr = __expf(mrow[r] - mn);
      mrow[r] = mn;
      float sm = 0.f;
      #pragma unroll
      for (int j = 0; j < 4; j++){
        float p = __expf(S[j][r] - mn);
        S[j][r] = p; sm += p;
      }
      #pragma unroll
      for (int off = 1; off < 16; off <<= 1) sm += __shfl_xor(sm, off);
      lrow[r] = lrow[r] * corr + sm;
      #pragma unroll
      for (int j = 0; j < 4; j++) O[j][r] *= corr;
    }
    #pragma unroll
    for (int j = 0; j < 4; j++)
      #pragma unroll
      for (int r = 0; r < 4; r++)
        P_lds[wid][l4*4 + r][j*16 + l15] = f2bf(S[j][r]);
    #pragma unroll
    for (int kk = 0; kk < 2; kk++){
      bf16x8 pa = *(const bf16x8*)(&P_lds[wid][l15][kk*32 + l4*8]);
      #pragma unroll
      for (int jd = 0; jd < 4; jd++){
        bf16x8 vf = *(const bf16x8*)(vh + (size_t)(jd*16 + l15) * TLEN
                                     + kv0 + kk*32 + l4*8);
        O[jd] = __builtin_amdgcn_mfma_f32_16x16x32_bf16(pa, vf, O[jd], 0, 0, 0);
      }
    }
  }

  #pragma unroll
  for (int r = 0; r < 4; r++){
    M_lds[wid][lane][r]     = mrow[r];
    M_lds[wid][lane][4 + r] = lrow[r];
  }
  #pragma unroll
  for (int jd = 0; jd < 4; jd++)
    #pragma unroll
    for (int r = 0; r < 4; r++)
      M_lds[wid][lane][8 + jd*4 + r] = O[jd][r];
  __syncthreads();

  if (wid == 0){
    float Mt[4], Lt[4];
    f32x4 Ot[4] = {};
    #pragma unroll
    for (int r = 0; r < 4; r++){
      Mt[r] = fmaxf(fmaxf(M_lds[0][lane][r], M_lds[1][lane][r]),
                    fmaxf(M_lds[2][lane][r], M_lds[3][lane][r]));
      Lt[r] = 0.f;
    }
    #pragma unroll
    for (int w = 0; w < 4; w++){
      #pragma unroll
      for (int r = 0; r < 4; r++){
        float c = __expf(M_lds[w][lane][r] - Mt[r]);
        Lt[r] += M_lds[w][lane][4 + r] * c;
        #pragma unroll
        for (int jd = 0; jd < 4; jd++)
          Ot[jd][r] += M_lds[w][lane][8 + jd*4 + r] * c;
      }
    }
    #pragma unroll
    for (int r = 0; r < 4; r++){
      float inv = 1.0f / Lt[r];
      int t = qb + l4*4 + r;
      #pragma unroll
      for (int jd = 0; jd < 4; jd++){
        int d = head * 64 + jd*16 + l15;
        h[(size_t)t * DM + d] += Ot[jd][r] * inv;
      }
    }
  }
}

extern "C" void kernel_launch(void* const* d_in, const int* in_sizes, int n_in,
                              void* d_out, int out_size, void* d_ws, size_t ws_size,
                              hipStream_t stream)
{
  const int*   x    = (const int*)  d_in[0];
  const float* wte  = (const float*)d_in[1];
  const float* wpe  = (const float*)d_in[2];
  const float* Wq   = (const float*)d_in[3];
  const float* bq   = (const float*)d_in[4];
  const float* Wk   = (const float*)d_in[5];
  const float* bk   = (const float*)d_in[6];
  const float* Wv   = (const float*)d_in[7];
  const float* bv   = (const float*)d_in[8];
  const float* ln1s = (const float*)d_in[9];
  const float* ln1b = (const float*)d_in[10];
  const float* W1   = (const float*)d_in[11];
  const float* b1   = (const float*)d_in[12];
  const float* W2   = (const float*)d_in[13];
  const float* b2   = (const float*)d_in[14];
  const float* ln2s = (const float*)d_in[15];
  const float* ln2b = (const float*)d_in[16];
  const float* lnfs = (const float*)d_in[17];
  const float* lnfb = (const float*)d_in[18];
  const float* Wlm  = (const float*)d_in[19];
  float* out = (float*)d_out;

  const size_t SZ_QKVT = (size_t)NL * 2304 * DM * 2;
  const size_t SZ_W1T  = (size_t)NL * DF_ * DM * 2;
  const size_t SZ_W2T  = (size_t)NL * DM * DF_ * 2;
  const size_t SZ_WLMT = (size_t)VCP * DM * 2;
  const size_t SZ_H    = (size_t)TLEN * DM * 4;   // fp32 h / partial
  const size_t SZ_BF   = (size_t)TLEN * DM * 2;   // bf16 activation

  char* ws = (char*)d_ws;
  short* wqkvT = (short*)ws;  ws += SZ_QKVT;
  short* w1T   = (short*)ws;  ws += SZ_W1T;
  short* w2T   = (short*)ws;  ws += SZ_W2T;
  short* wlmT  = (short*)ws;  ws += SZ_WLMT;
  float* h     = (float*)ws;  ws += SZ_H;
  short* qb    = (short*)ws;  ws += SZ_BF;
  short* kb    = (short*)ws;  ws += SZ_BF;
  short* vtb   = (short*)ws;  ws += SZ_BF;
  short* xnb   = (short*)ws;  ws += SZ_BF;
  short* mhb   = (short*)ws;  ws += (size_t)TLEN * DF_ * 2;
  float* p1    = (float*)ws;  // fresh 3 MB
  float* p0    = (float*)qb;  // overlays qb+kb (dead during MLP2/redln)
  // p2/p3 live in d_out: dead until the LM head, which later overwrites
  // every element (all rows, cols < VC). Written before read each call.
  float* p2    = out;
  float* p3    = out + (size_t)TLEN * DM;

  tcqkv_k<<<NL*NH*12, 256, 0, stream>>>(Wq, Wk, Wv, wqkvT);
  tc_k<<<NL*48*12, 256, 0, stream>>>(W1, w1T, DM, DF_, 48, 576,
                                     (size_t)DM*DF_, (size_t)DM*DF_);
  tc_k<<<NL*12*48, 256, 0, stream>>>(W2, w2T, DF_, DM, 12, 576,
                                     (size_t)DM*DF_, (size_t)DM*DF_);
  tc_k<<<786*12, 256, 0, stream>>>(Wlm, wlmT, DM, VC, 786, 786*12, 0, 0);

  embedln_k<<<TLEN/4, 256, 0, stream>>>(x, wte, wpe, ln1s, ln1b, h, xnb);

  for (int l = 0; l < NL; ++l){
    mg_k<0,2,2,64><<<dim3(16,36), 256, 0, stream>>>(xnb, wqkvT + (size_t)l*2304*DM,
        bq + l*DM, bk + l*DM, bv + l*DM, qb, kb, vtb);
    attn_k<<<NH*64, 256, 0, stream>>>(qb, kb, vtb, h);
    ln_k<<<TLEN/4, 256, 0, stream>>>(h, ln2s + l*DM, ln2b + l*DM, xnb);
    mg_k<1,2,2,64><<<dim3(16,48), 256, 0, stream>>>(xnb, w1T + (size_t)l*DF_*DM,
        b1 + l*DF_, nullptr, nullptr, mhb, nullptr, nullptr);
    // MLP2 split-K z=4: 768 blocks = perfect machine fill; p3 rides in b0
    mg_k<2,2,2,64><<<dim3(16,12,4), 256, 0, stream>>>(mhb, w2T + (size_t)l*DM*DF_,
        p3, nullptr, nullptr, p0, p1, p2);
    const float* nsc = (l < NL-1) ? ln1s + (l+1)*DM : lnfs;
    const float* nbi = (l < NL-1) ? ln1b + (l+1)*DM : lnfb;
    redln_k<<<TLEN/4, 256, 0, stream>>>(h, p0, p1, p2, p3, b2 + l*DM, nsc, nbi, xnb);
  }

  // LM head: 128x128 XCD-pinned, BK=32 DEPTH=2 (r17 config)
  mg_k<3,4,4,32><<<3200, 256, 0, stream>>>(xnb, wlmT,
      nullptr, nullptr, nullptr, out, nullptr, nullptr);
}